// Round 5
// baseline (5866.390 us; speedup 1.0000x reference)
//
#include <hip/hip_runtime.h>
#include <cmath>
#include <complex>
#include <cstring>
#include <cstdint>

#define NN 50000
#define NE 600000

#define ISN 0.51298917604257706f
#define RN  1.4142135623730951f

// ---- CG table offsets (flattened, [d1][d2][d3] row-major) ----
#define CG000 0
#define CG110 1
#define CG220 10
#define CG330 35
#define CG011 84
#define CG101 93
#define CG121 102
#define CG211 147
#define CG231 192
#define CG321 297
#define CG111 402
#define CG221 429
#define CG331 504
#define CGTOT 651

struct CGTab { float v[CGTOT]; };

// ===================== host: real Wigner-3j (mirrors reference) =====================
static double factd(int n){ double r=1.0; for(int i=2;i<=n;++i) r*=(double)i; return r; }

static void cg_complex_h(int j1,int j2,int j3,double* C){
  const int d2=2*j2+1, d3=2*j3+1;
  const int tot=(2*j1+1)*d2*d3;
  for(int i=0;i<tot;++i) C[i]=0.0;
  for(int m1=-j1;m1<=j1;++m1) for(int m2=-j2;m2<=j2;++m2){
    int m3=m1+m2; if(m3<-j3||m3>j3) continue;
    double pref=std::sqrt((double)(2*j3+1)*factd(j3+j1-j2)*factd(j3-j1+j2)*factd(j1+j2-j3)/factd(j1+j2+j3+1));
    pref*=std::sqrt(factd(j3+m3)*factd(j3-m3)*factd(j1-m1)*factd(j1+m1)*factd(j2-m2)*factd(j2+m2));
    double s=0.0;
    for(int k=0;k<=j1+j2-j3;++k){
      int a1=j1+j2-j3-k,a2=j1-m1-k,a3=j2+m2-k,a4=j3-j2+m1+k,a5=j3-j1-m2+k;
      if(a1<0||a2<0||a3<0||a4<0||a5<0) continue;
      double pr=factd(k)*factd(a1)*factd(a2)*factd(a3)*factd(a4)*factd(a5);
      s+=((k&1)?-1.0:1.0)/pr;
    }
    C[(m1+j1)*d2*d3+(m2+j2)*d3+(m3+j3)]=pref*s;
  }
}

typedef std::complex<double> cdbl;

static void real_change_h(int l, cdbl* A){
  int d=2*l+1;
  for(int i=0;i<d*d;++i) A[i]=cdbl(0,0);
  A[l*d+l]=cdbl(1,0);
  const double is2=1.0/std::sqrt(2.0);
  for(int m=1;m<=l;++m){
    double sg=(m&1)?-1.0:1.0;
    A[(l+m)*d+(l-m)]=cdbl(is2,0);
    A[(l+m)*d+(l+m)]=cdbl(sg*is2,0);
    A[(l-m)*d+(l-m)]=cdbl(0,is2);
    A[(l-m)*d+(l+m)]=cdbl(0,-sg*is2);
  }
}

static void real_w3j_h(int l1,int l2,int l3,float* R){
  const int d1=2*l1+1,d2=2*l2+1,d3=2*l3+1;
  double cg[512]; cg_complex_h(l1,l2,l3,cg);
  double w[512];
  for(int a=0;a<d1;++a)for(int b=0;b<d2;++b)for(int m3=-l3;m3<=l3;++m3){
    double sg=((l1-l2-m3)&1)?-1.0:1.0;
    w[a*d2*d3+b*d3+(m3+l3)]=sg/std::sqrt((double)(2*l3+1))*cg[a*d2*d3+b*d3+(-m3+l3)];
  }
  cdbl A1[49],A2[49],A3[49];
  real_change_h(l1,A1); real_change_h(l2,A2); real_change_h(l3,A3);
  double nre=0.0,nim=0.0;
  cdbl T[512];
  for(int i=0;i<d1;++i)for(int j=0;j<d2;++j)for(int k=0;k<d3;++k){
    cdbl s(0,0);
    for(int a=0;a<d1;++a){ cdbl f1=A1[i*d1+a];
      if(f1.real()==0.0&&f1.imag()==0.0) continue;
      for(int b=0;b<d2;++b){ cdbl f2=A2[j*d2+b];
        if(f2.real()==0.0&&f2.imag()==0.0) continue;
        cdbl f12=f1*f2;
        for(int c=0;c<d3;++c){ cdbl f3=A3[k*d3+c];
          if(f3.real()==0.0&&f3.imag()==0.0) continue;
          s+=f12*f3*w[a*d2*d3+b*d3+c];
        }
      }
    }
    T[i*d2*d3+j*d3+k]=s;
    nre+=s.real()*s.real(); nim+=s.imag()*s.imag();
  }
  bool useRe = std::sqrt(nre)>=std::sqrt(nim);
  for(int i=0;i<d1*d2*d3;++i) R[i]=(float)(useRe?T[i].real():T[i].imag());
}

static void build_cg(CGTab& t){
  struct E{int l1,l2,l3,off;};
  const E es[13]={{0,0,0,CG000},{1,1,0,CG110},{2,2,0,CG220},{3,3,0,CG330},
    {0,1,1,CG011},{1,0,1,CG101},{1,2,1,CG121},{2,1,1,CG211},{2,3,1,CG231},
    {3,2,1,CG321},{1,1,1,CG111},{2,2,1,CG221},{3,3,1,CG331}};
  for(int i=0;i<13;++i) real_w3j_h(es[i].l1,es[i].l2,es[i].l3,t.v+es[i].off);
}

// ===================== device helpers =====================
__device__ __forceinline__ void atomicAddF(float* p, float v){
  unsafeAtomicAdd(p, v);
}
__device__ __forceinline__ void ld16f(const float* p, float* d){
  const float4* q=(const float4*)p;
  #pragma unroll
  for(int i=0;i<4;++i){ float4 t=q[i]; d[4*i]=t.x; d[4*i+1]=t.y; d[4*i+2]=t.z; d[4*i+3]=t.w; }
}

// ===================== k_pack: gather/prescale live columns of w2c/w2f =====================
// w2cp: [256][224]  (200 live cols, pad 0)   w2fp: [256][160] (152 live, pad 0)
__global__ void k_pack(const float* __restrict__ w2c, const float* __restrict__ w2f,
                       float* __restrict__ w2cp, float* __restrict__ w2fp){
  int idx = blockIdx.x*256 + threadIdx.x;   // grid 384*256 = 98304 exact
  const float Sc = (float)(1.4142135623730951/(16.0*sqrt(3.0))/sqrt(3.8));
  const float Sf = (float)(1.4142135623730951/(16.0*sqrt(3.0))/sqrt(3.8)*0.5);
  const float A_ = (float)sqrt(0.5);
  const float B_ = (float)sqrt(1.0/48.0);
  if (idx < 256*224){
    int row=idx/224, c=idx%224;
    float v=0.f;
    if (c<200){
      int oc; float s;
      if (c<128){ oc=c; s=0.5f; }
      else if (c<176){ int p=(c-128)>>3, m=(c-128)&7; oc=128+16*p+m; s=A_; }
      else { int p=(c-176)>>3, m=(c-176)&7; oc=224+16*p+m; s=1.0f; }
      v = w2c[row*272+oc]*(Sc*s);
    }
    w2cp[idx]=v;
  } else {
    idx -= 256*224;
    int row=idx/160, c=idx%160;
    float v=0.f;
    if (c<152){
      int oc; float s;
      if (c<8){ oc=8+c; s=0.25f; }
      else if (c<104){ oc=16+(c-8); s=B_; }
      else { oc=208+(c-104); s=B_; }
      v = w2f[row*304+oc]*(Sf*s);
    }
    w2fp[idx]=v;
  }
}

// ===================== k_geom: per-edge SH + length, atomic x0 =====================
__global__ void k_geom(const float* __restrict__ pos, const int* __restrict__ esrc,
                       const int* __restrict__ edst, float* __restrict__ lenb,
                       float* __restrict__ shb, float* __restrict__ x0){
  int e = blockIdx.x*256+threadIdx.x;
  if (e>=NE) return;
  int s=esrc[e], d=edst[e];
  float vx=pos[3*s]-pos[3*d], vy=pos[3*s+1]-pos[3*d+1], vz=pos[3*s+2]-pos[3*d+2];
  float len=sqrtf(vx*vx+vy*vy+vz*vz);
  float inv=1.0f/fmaxf(len,1e-9f);
  float x=vx*inv, y=vy*inv, z=vz*inv;
  float x2=x*x, y2=y*y, z2=z*z;
  float sh[16];
  sh[0]=1.0f;
  sh[1]=1.7320508f*y; sh[2]=1.7320508f*z; sh[3]=1.7320508f*x;
  sh[4]=3.8729833f*x*y; sh[5]=3.8729833f*y*z; sh[6]=1.1180340f*(3.0f*z2-1.0f);
  sh[7]=3.8729833f*x*z; sh[8]=1.9364917f*(x2-y2);
  sh[9]=2.0916501f*y*(3.0f*x2-y2); sh[10]=10.2469508f*x*y*z;
  sh[11]=1.6201852f*y*(5.0f*z2-1.0f); sh[12]=1.3228757f*z*(5.0f*z2-3.0f);
  sh[13]=1.6201852f*x*(5.0f*z2-1.0f); sh[14]=5.1234754f*z*(x2-y2);
  sh[15]=2.0916501f*x*(x2-3.0f*y2);
  lenb[e]=len;
  float4* sp=(float4*)(shb+(size_t)16*e);
  sp[0]=make_float4(sh[0],sh[1],sh[2],sh[3]);
  sp[1]=make_float4(sh[4],sh[5],sh[6],sh[7]);
  sp[2]=make_float4(sh[8],sh[9],sh[10],sh[11]);
  sp[3]=make_float4(sh[12],sh[13],sh[14],sh[15]);
  float* xb=x0+(size_t)16*d;
  #pragma unroll
  for(int i=0;i<16;++i) atomicAddF(xb+i, sh[i]*ISN);
}

// ===================== k_gemm_c: per-edge weights GEMM, tile 128 edges x 224 cols =====================
// LDS 45KB -> 3 blocks/CU. Writes wb[el][224] (el = local edge in stripe).
__global__ __launch_bounds__(256)
void k_gemm_c(const float* __restrict__ lenb, const float* __restrict__ w1,
              const float* __restrict__ w2p, float* __restrict__ wb, int ebase){
  __shared__ float hA[32][128];
  __shared__ float w2s[32][224];
  const int tid=threadIdx.x;
  const int sub=tid&7, kk0=tid>>3;
  const int tn=tid&15, tm=tid>>4;
  const int ebl = blockIdx.x*128;

  float em0[16],em1[16],em2[16];
  #pragma unroll
  for(int i=0;i<16;++i){
    int ei = ebase + ebl + 16*sub + i;
    float len = (ei<NE)? lenb[ei] : 1.0f;
    float t0=2.0f*(len-1.0f), t1=2.0f*(len-1.5f), t2=2.0f*(len-2.0f);
    em0[i]=expf(-t0*t0)*1.7320508f;
    em1[i]=expf(-t1*t1)*1.7320508f;
    em2[i]=expf(-t2*t2)*1.7320508f;
  }

  float acc[8][14];
  #pragma unroll
  for(int r=0;r<8;++r)
    #pragma unroll
    for(int c=0;c<14;++c) acc[r][c]=0.f;

  for(int kc=0;kc<8;++kc){
    {
      int K=kc*32+kk0;
      float a=w1[K], b=w1[256+K], c=w1[512+K];
      #pragma unroll
      for(int g=0;g<4;++g){
        float h0=fmaxf(em0[4*g+0]*a+em1[4*g+0]*b+em2[4*g+0]*c,0.f);
        float h1=fmaxf(em0[4*g+1]*a+em1[4*g+1]*b+em2[4*g+1]*c,0.f);
        float h2=fmaxf(em0[4*g+2]*a+em1[4*g+2]*b+em2[4*g+2]*c,0.f);
        float h3=fmaxf(em0[4*g+3]*a+em1[4*g+3]*b+em2[4*g+3]*c,0.f);
        *(float4*)&hA[kk0][16*sub+4*g]=make_float4(h0,h1,h2,h3);
      }
    }
    {
      const float4* src=(const float4*)(w2p+(size_t)kc*32*224);
      float4* dst=(float4*)&w2s[0][0];
      #pragma unroll
      for(int i=0;i<7;++i) dst[tid+256*i]=src[tid+256*i];
    }
    __syncthreads();
    #pragma unroll
    for(int kk=0;kk<32;++kk){
      float4 av0=*(const float4*)&hA[kk][8*tm];
      float4 av1=*(const float4*)&hA[kk][8*tm+4];
      float b[14];
      #pragma unroll
      for(int s=0;s<7;++s){ float2 bv=*(const float2*)&w2s[kk][14*tn+2*s]; b[2*s]=bv.x; b[2*s+1]=bv.y; }
      #pragma unroll
      for(int c=0;c<14;++c){
        acc[0][c]+=av0.x*b[c]; acc[1][c]+=av0.y*b[c]; acc[2][c]+=av0.z*b[c]; acc[3][c]+=av0.w*b[c];
        acc[4][c]+=av1.x*b[c]; acc[5][c]+=av1.y*b[c]; acc[6][c]+=av1.z*b[c]; acc[7][c]+=av1.w*b[c];
      }
    }
    __syncthreads();
  }

  #pragma unroll
  for(int r=0;r<8;++r){
    int el = ebl + 8*tm + r;
    if (ebase + el < NE){
      float* row = wb + (size_t)el*224 + 14*tn;
      #pragma unroll
      for(int s=0;s<7;++s) *(float2*)&row[2*s]=make_float2(acc[r][2*s],acc[r][2*s+1]);
    }
  }
}

// ===================== k_tp_c: per-edge TP + scatter x1[80]; 4 waves = 4 col-groups =====================
__global__ __launch_bounds__(256)
void k_tp_c(const int* __restrict__ esrc, const int* __restrict__ edst,
            const float* __restrict__ shb, const float* __restrict__ x0,
            const float* __restrict__ wb, int ebase, CGTab cgt, float* __restrict__ x1){
  __shared__ float sh8[64][9];     // wv1 -> wv0 (ch 8..15 partial)
  __shared__ float sh1o[64][24];   // wv3 -> wv2 (1o p5 partial)
  const int tid=threadIdx.x, wv=tid>>6, lane=tid&63;
  const int el = blockIdx.x*64 + lane;
  const int eabs = ebase + el;
  const bool alive = (eabs < NE);
  int dstn=0;
  float efA[24], efX[8];
  #pragma unroll
  for(int i=0;i<24;++i) efA[i]=0.f;
  #pragma unroll
  for(int i=0;i<8;++i) efX[i]=0.f;

  if (alive){
    int srcn=esrc[eabs]; dstn=edst[eabs];
    float s1[16], s2[16];
    ld16f(x0+(size_t)16*srcn, s1);
    ld16f(shb+(size_t)16*eabs, s2);
    const float* wr = wb + (size_t)el*224 + 56*wv;

    if (wv<=2){
      // T scalars (paths (l,l)->0e)
      float T[4];
      T[0]=s1[0]*s2[0]*cgt.v[CG000];
      T[1]=0.f;
      #pragma unroll
      for(int a=0;a<3;++a)
        #pragma unroll
        for(int b=0;b<3;++b) T[1]+=s1[1+a]*s2[1+b]*cgt.v[CG110+3*a+b];
      T[2]=0.f;
      #pragma unroll
      for(int a=0;a<5;++a)
        #pragma unroll
        for(int b=0;b<5;++b) T[2]+=s1[4+a]*s2[4+b]*cgt.v[CG220+5*a+b];
      T[3]=0.f;
      #pragma unroll
      for(int a=0;a<7;++a)
        #pragma unroll
        for(int b=0;b<7;++b) T[3]+=s1[9+a]*s2[9+b]*cgt.v[CG330+7*a+b];

      if (wv==0){
        // cols 0..55: ch (c&15) <- T[c>>4]
        #pragma unroll
        for(int i=0;i<14;++i){
          float4 w4=((const float4*)wr)[i];
          float wa[4]={w4.x,w4.y,w4.z,w4.w};
          #pragma unroll
          for(int t=0;t<4;++t){ int c=4*i+t; efA[c&15]+=wa[t]*T[c>>4]; }
        }
      } else if (wv==1){
        // cols 56..111
        float ef8[8];
        #pragma unroll
        for(int i=0;i<8;++i) ef8[i]=0.f;
        #pragma unroll
        for(int i=0;i<14;++i){
          float4 w4=((const float4*)wr)[i];
          float wa[4]={w4.x,w4.y,w4.z,w4.w};
          #pragma unroll
          for(int t=0;t<4;++t){
            int c=4*i+t;                 // 0..55 (j = 56+c)
            if (c<8)        ef8[c]        += wa[t]*T[3];           // j 56..63 -> ch 8..15
            else if (c<40)  efA[(c-8)&7]  += wa[t]*T[(c-8)>>3];    // io2 -> ch16..23
            else            efX[(c-40)&7] += wa[t]*T[(c-40)>>3];   // io4 p0,p1 -> ch24..31
          }
        }
        #pragma unroll
        for(int i=0;i<8;++i) sh8[lane][i]=ef8[i];
      } else {
        // wv==2: cols 112..167
        float T1o[5][3];
        #pragma unroll
        for(int p=0;p<5;++p)
          #pragma unroll
          for(int k=0;k<3;++k) T1o[p][k]=0.f;
        #pragma unroll
        for(int b=0;b<3;++b){ float pr=s1[0]*s2[1+b];
          #pragma unroll
          for(int k=0;k<3;++k) T1o[0][k]+=pr*cgt.v[CG011+3*b+k]; }
        #pragma unroll
        for(int a=0;a<3;++a){ float pr=s1[1+a]*s2[0];
          #pragma unroll
          for(int k=0;k<3;++k) T1o[1][k]+=pr*cgt.v[CG101+3*a+k]; }
        #pragma unroll
        for(int a=0;a<3;++a)
          #pragma unroll
          for(int b=0;b<5;++b){ float pr=s1[1+a]*s2[4+b];
            #pragma unroll
            for(int k=0;k<3;++k) T1o[2][k]+=pr*cgt.v[CG121+(5*a+b)*3+k]; }
        #pragma unroll
        for(int a=0;a<5;++a)
          #pragma unroll
          for(int b=0;b<3;++b){ float pr=s1[4+a]*s2[1+b];
            #pragma unroll
            for(int k=0;k<3;++k) T1o[3][k]+=pr*cgt.v[CG211+(3*a+b)*3+k]; }
        #pragma unroll
        for(int a=0;a<5;++a)
          #pragma unroll
          for(int b=0;b<7;++b){ float pr=s1[4+a]*s2[9+b];
            #pragma unroll
            for(int k=0;k<3;++k) T1o[4][k]+=pr*cgt.v[CG231+(7*a+b)*3+k]; }
        #pragma unroll
        for(int i=0;i<14;++i){
          float4 w4=((const float4*)wr)[i];
          float wa[4]={w4.x,w4.y,w4.z,w4.w};
          #pragma unroll
          for(int t=0;t<4;++t){
            int c=4*i+t;                 // j = 112+c
            if (c<16){
              efX[c&7] += wa[t]*T[2+(c>>3)];      // io4 p2,p3 -> ch24..31
            } else {
              int loc=c-16; int p=loc>>3, m=loc&7; // 1o p0..4 -> ch32+3m+k
              #pragma unroll
              for(int k=0;k<3;++k) efA[3*m+k]+=wa[t]*T1o[p][k];
            }
          }
        }
      }
    } else {
      // wv==3: cols 168..199 (8 f4 loads)
      float T321[3]={0.f,0.f,0.f};
      #pragma unroll
      for(int a=0;a<7;++a)
        #pragma unroll
        for(int b=0;b<5;++b){ float pr=s1[9+a]*s2[4+b];
          #pragma unroll
          for(int k=0;k<3;++k) T321[k]+=pr*cgt.v[CG321+(5*a+b)*3+k]; }
      float T1e[3][3];
      #pragma unroll
      for(int p=0;p<3;++p)
        #pragma unroll
        for(int k=0;k<3;++k) T1e[p][k]=0.f;
      #pragma unroll
      for(int a=0;a<3;++a)
        #pragma unroll
        for(int b=0;b<3;++b){ float pr=s1[1+a]*s2[1+b];
          #pragma unroll
          for(int k=0;k<3;++k) T1e[0][k]+=pr*cgt.v[CG111+(3*a+b)*3+k]; }
      #pragma unroll
      for(int a=0;a<5;++a)
        #pragma unroll
        for(int b=0;b<5;++b){ float pr=s1[4+a]*s2[4+b];
          #pragma unroll
          for(int k=0;k<3;++k) T1e[1][k]+=pr*cgt.v[CG221+(5*a+b)*3+k]; }
      #pragma unroll
      for(int a=0;a<7;++a)
        #pragma unroll
        for(int b=0;b<7;++b){ float pr=s1[9+a]*s2[9+b];
          #pragma unroll
          for(int k=0;k<3;++k) T1e[2][k]+=pr*cgt.v[CG331+(7*a+b)*3+k]; }
      #pragma unroll
      for(int i=0;i<8;++i){
        float4 w4=((const float4*)wr)[i];
        float wa[4]={w4.x,w4.y,w4.z,w4.w};
        #pragma unroll
        for(int t=0;t<4;++t){
          int c=4*i+t;                   // j = 168+c
          if (c<8){
            // 1o p5, exactly one col per m=c
            #pragma unroll
            for(int k=0;k<3;++k) sh1o[lane][3*c+k]=wa[t]*T321[k];
          } else {
            int loc2=c-8; int p=loc2>>3, m=loc2&7;  // 1e -> ch56+3m+k
            #pragma unroll
            for(int k=0;k<3;++k) efA[3*m+k]+=wa[t]*T1e[p][k];
          }
        }
      }
    }
  }
  __syncthreads();
  if (alive){
    float* ob = x1 + (size_t)80*dstn;
    if (wv==0){
      #pragma unroll
      for(int i=0;i<8;++i) efA[8+i]+=sh8[lane][i];
      #pragma unroll
      for(int i=0;i<16;++i) atomicAddF(ob+i, efA[i]);
    } else if (wv==1){
      #pragma unroll
      for(int i=0;i<8;++i) atomicAddF(ob+16+i, efA[i]);
      #pragma unroll
      for(int i=0;i<8;++i) atomicAddF(ob+24+i, efX[i]);
    } else if (wv==2){
      #pragma unroll
      for(int i=0;i<24;++i){ efA[i]+=sh1o[lane][i]; atomicAddF(ob+32+i, efA[i]); }
      #pragma unroll
      for(int i=0;i<8;++i) atomicAddF(ob+24+i, efX[i]);
    } else {
      #pragma unroll
      for(int i=0;i<24;++i) atomicAddF(ob+56+i, efA[i]);
    }
  }
}

// ===================== k_gate: compact x1[80] -> xg[64] =====================
__global__ void k_gate(const float* __restrict__ x1, float* __restrict__ xg){
  int n=blockIdx.x*256+threadIdx.x;
  if (n>=NN) return;
  float v[80];
  const float4* p=(const float4*)(x1+(size_t)80*n);
  #pragma unroll
  for(int i=0;i<20;++i){ float4 q=p[i]; v[4*i]=q.x; v[4*i+1]=q.y; v[4*i+2]=q.z; v[4*i+3]=q.w; }
  float o[64];
  #pragma unroll
  for(int i=0;i<16;++i) o[i]=fmaxf(v[i],0.f)*RN;
  #pragma unroll
  for(int r=0;r<8;++r){ float g=fmaxf(v[16+r],0.f)*RN;
    #pragma unroll
    for(int k=0;k<3;++k) o[16+3*r+k]=v[32+3*r+k]*g; }
  #pragma unroll
  for(int r=0;r<8;++r){ float g=fmaxf(v[24+r],0.f)*RN;
    #pragma unroll
    for(int k=0;k<3;++k) o[40+3*r+k]=v[56+3*r+k]*g; }
  float4* q=(float4*)(xg+(size_t)64*n);
  #pragma unroll
  for(int i=0;i<16;++i) q[i]=make_float4(o[4*i],o[4*i+1],o[4*i+2],o[4*i+3]);
}

// ===================== k_gemm_f: final weights GEMM, tile 128 x 160 =====================
__global__ __launch_bounds__(256)
void k_gemm_f(const float* __restrict__ lenb, const float* __restrict__ w1,
              const float* __restrict__ w2p, float* __restrict__ wb, int ebase){
  __shared__ float hA[32][128];
  __shared__ float w2s[32][160];
  const int tid=threadIdx.x;
  const int sub=tid&7, kk0=tid>>3;
  const int tn=tid&15, tm=tid>>4;
  const int ebl = blockIdx.x*128;

  float em0[16],em1[16],em2[16];
  #pragma unroll
  for(int i=0;i<16;++i){
    int ei = ebase + ebl + 16*sub + i;
    float len = (ei<NE)? lenb[ei] : 1.0f;
    float t0=2.0f*(len-1.0f), t1=2.0f*(len-1.5f), t2=2.0f*(len-2.0f);
    em0[i]=expf(-t0*t0)*1.7320508f;
    em1[i]=expf(-t1*t1)*1.7320508f;
    em2[i]=expf(-t2*t2)*1.7320508f;
  }

  float acc[8][10];
  #pragma unroll
  for(int r=0;r<8;++r)
    #pragma unroll
    for(int c=0;c<10;++c) acc[r][c]=0.f;

  for(int kc=0;kc<8;++kc){
    {
      int K=kc*32+kk0;
      float a=w1[K], b=w1[256+K], c=w1[512+K];
      #pragma unroll
      for(int g=0;g<4;++g){
        float h0=fmaxf(em0[4*g+0]*a+em1[4*g+0]*b+em2[4*g+0]*c,0.f);
        float h1=fmaxf(em0[4*g+1]*a+em1[4*g+1]*b+em2[4*g+1]*c,0.f);
        float h2=fmaxf(em0[4*g+2]*a+em1[4*g+2]*b+em2[4*g+2]*c,0.f);
        float h3=fmaxf(em0[4*g+3]*a+em1[4*g+3]*b+em2[4*g+3]*c,0.f);
        *(float4*)&hA[kk0][16*sub+4*g]=make_float4(h0,h1,h2,h3);
      }
    }
    {
      const float4* src=(const float4*)(w2p+(size_t)kc*32*160);
      float4* dst=(float4*)&w2s[0][0];
      #pragma unroll
      for(int i=0;i<5;++i) dst[tid+256*i]=src[tid+256*i];
    }
    __syncthreads();
    #pragma unroll
    for(int kk=0;kk<32;++kk){
      float4 av0=*(const float4*)&hA[kk][8*tm];
      float4 av1=*(const float4*)&hA[kk][8*tm+4];
      float b[10];
      #pragma unroll
      for(int s=0;s<5;++s){ float2 bv=*(const float2*)&w2s[kk][10*tn+2*s]; b[2*s]=bv.x; b[2*s+1]=bv.y; }
      #pragma unroll
      for(int c=0;c<10;++c){
        acc[0][c]+=av0.x*b[c]; acc[1][c]+=av0.y*b[c]; acc[2][c]+=av0.z*b[c]; acc[3][c]+=av0.w*b[c];
        acc[4][c]+=av1.x*b[c]; acc[5][c]+=av1.y*b[c]; acc[6][c]+=av1.z*b[c]; acc[7][c]+=av1.w*b[c];
      }
    }
    __syncthreads();
  }

  #pragma unroll
  for(int r=0;r<8;++r){
    int el = ebl + 8*tm + r;
    if (ebase + el < NE){
      float* row = wb + (size_t)el*160 + 10*tn;
      #pragma unroll
      for(int s=0;s<5;++s) *(float2*)&row[2*s]=make_float2(acc[r][2*s],acc[r][2*s+1]);
    }
  }
}

// ===================== k_tp_f: per-edge final TP -> graph reduce =====================
// 2 col-groups per edge (q = wave&1), 128 edges/block, grid-stride over groups.
__global__ __launch_bounds__(256)
void k_tp_f(const int* __restrict__ esrc, const int* __restrict__ edst,
            const float* __restrict__ shb, const float* __restrict__ xg,
            const float* __restrict__ wb, int ebase, int ngroups, CGTab cgt,
            const int* __restrict__ batch, float* __restrict__ out){
  __shared__ float gacc[16][8];
  const int tid=threadIdx.x;
  if (tid<128) ((float*)gacc)[tid]=0.f;
  __syncthreads();
  const int lane=tid&63, wv=tid>>6;
  const int q=wv&1, half=wv>>1;

  for (int g=blockIdx.x; g<ngroups; g+=gridDim.x){
    int el = g*128 + half*64 + lane;
    int eabs = ebase + el;
    if (eabs < NE){
      int srcn=esrc[eabs], dstn=edst[eabs];
      int gidx=batch[dstn];
      const float* yp = xg + (size_t)64*srcn;
      float4 s4=*(const float4*)(shb+(size_t)16*eabs);
      float c000=cgt.v[CG000];
      const float* wr = wb + (size_t)el*160;
      float ef[7]={0.f,0.f,0.f,0.f,0.f,0.f,0.f};
      if (q==0){
        // cols 0..79: tA (0..7), du u=0..11 (8..79)
        float y0[12];
        { const float4* p=(const float4*)yp;
          #pragma unroll
          for(int i=0;i<3;++i){ float4 t=p[i]; y0[4*i]=t.x; y0[4*i+1]=t.y; y0[4*i+2]=t.z; y0[4*i+3]=t.w; } }
        float yA[24];
        { const float4* p=(const float4*)(yp+40);
          #pragma unroll
          for(int i=0;i<6;++i){ float4 t=p[i]; yA[4*i]=t.x; yA[4*i+1]=t.y; yA[4*i+2]=t.z; yA[4*i+3]=t.w; } }
        float du[12];
        #pragma unroll
        for(int u=0;u<12;++u) du[u]=y0[u]*s4.x*c000;
        float shv[3]={s4.y,s4.z,s4.w};
        float tA[8];
        #pragma unroll
        for(int u=0;u<8;++u){
          float sa=0.f;
          #pragma unroll
          for(int a=0;a<3;++a)
            #pragma unroll
            for(int b=0;b<3;++b) sa+=yA[3*u+a]*shv[b]*cgt.v[CG110+3*a+b];
          tA[u]=sa;
        }
        #pragma unroll
        for(int i=0;i<20;++i){
          float4 w4=((const float4*)wr)[i];
          float wa[4]={w4.x,w4.y,w4.z,w4.w};
          #pragma unroll
          for(int t=0;t<4;++t){
            int c=4*i+t;
            if (c<8) ef[0]+=wa[t]*tA[c];
            else { int loc=c-8; ef[1+loc%6]+=wa[t]*du[loc/6]; }
          }
        }
      } else {
        // cols 80..151: du u=12..15 (80..103), tC (104..151)
        float y1[4];
        { float4 t=*(const float4*)(yp+12); y1[0]=t.x;y1[1]=t.y;y1[2]=t.z;y1[3]=t.w; }
        float yC[24];
        { const float4* p=(const float4*)(yp+16);
          #pragma unroll
          for(int i=0;i<6;++i){ float4 t=p[i]; yC[4*i]=t.x; yC[4*i+1]=t.y; yC[4*i+2]=t.z; yC[4*i+3]=t.w; } }
        float du2[4];
        #pragma unroll
        for(int u=0;u<4;++u) du2[u]=y1[u]*s4.x*c000;
        float shv[3]={s4.y,s4.z,s4.w};
        float tC[8];
        #pragma unroll
        for(int u=0;u<8;++u){
          float sc=0.f;
          #pragma unroll
          for(int a=0;a<3;++a)
            #pragma unroll
            for(int b=0;b<3;++b) sc+=yC[3*u+a]*shv[b]*cgt.v[CG110+3*a+b];
          tC[u]=sc;
        }
        const float4* wr4=(const float4*)(wr+80);
        #pragma unroll
        for(int i=0;i<18;++i){
          float4 w4=wr4[i];
          float wa[4]={w4.x,w4.y,w4.z,w4.w};
          #pragma unroll
          for(int t=0;t<4;++t){
            int c=80+4*i+t;
            if (c<104){ int loc=c-8; ef[1+loc%6]+=wa[t]*du2[loc/6-12]; }
            else { int loc2=c-104; ef[1+loc2%6]+=wa[t]*tC[loc2/6]; }
          }
        }
      }
      #pragma unroll
      for(int oc=0;oc<7;++oc) atomicAdd(&gacc[gidx][oc], ef[oc]);
    }
  }
  __syncthreads();
  if (tid<112) atomicAddF(out+tid, gacc[tid/7][tid%7]);
}

// ===================== launch =====================
extern "C" void kernel_launch(void* const* d_in, const int* in_sizes, int n_in,
                              void* d_out, int out_size, void* d_ws, size_t ws_size,
                              hipStream_t stream) {
  (void)in_sizes; (void)n_in; (void)out_size;
  const float* pos  = (const float*)d_in[0];
  const int*   batch= (const int*)d_in[1];
  const int*   esrc = (const int*)d_in[2];
  const int*   edst = (const int*)d_in[3];
  const float* w1c  = (const float*)d_in[4];
  const float* w2c  = (const float*)d_in[5];
  const float* w1f  = (const float*)d_in[6];
  const float* w2f  = (const float*)d_in[7];
  float* out = (float*)d_out;
  char* ws = (char*)d_ws;

  const size_t OFF_W2CP = 0;            // 256*224*4 = 229376
  const size_t OFF_W2FP = 229376;       // 256*160*4 = 163840
  const size_t OFF_LEN  = 393216;       // NE*4      = 2400000
  const size_t OFF_SH   = 2793216;      // NE*16*4   = 38400000
  const size_t OFF_X0   = 41193216;     // NN*16*4   = 3200000
  const size_t OFF_X1   = 44393216;     // NN*80*4   = 16000000
  const size_t OFF_XG   = 60393216;     // NN*64*4   = 12800000
  const size_t OFF_WB   = 73193216;     // striped per-edge weight buffer

  float* w2cp=(float*)(ws+OFF_W2CP);
  float* w2fp=(float*)(ws+OFF_W2FP);
  float* lenb=(float*)(ws+OFF_LEN);
  float* shb =(float*)(ws+OFF_SH);
  float* x0  =(float*)(ws+OFF_X0);
  float* x1  =(float*)(ws+OFF_X1);
  float* xg  =(float*)(ws+OFF_XG);
  float* wb  =(float*)(ws+OFF_WB);

  // stripe sizing against available workspace (ws_size is constant -> capture-safe)
  size_t avail = (ws_size > OFF_WB) ? (ws_size - OFF_WB) : 0;
  long long stripeC = (long long)(avail / (224*4)); stripeC = (stripeC/128)*128;
  if (stripeC < 128) stripeC = 128;
  if (stripeC > 600064) stripeC = 600064;
  long long stripeF = (long long)(avail / (160*4)); stripeF = (stripeF/128)*128;
  if (stripeF < 128) stripeF = 128;
  if (stripeF > 600064) stripeF = 600064;

  static CGTab hostCG;
  build_cg(hostCG);   // deterministic; travels as kernarg

  hipMemsetAsync(x0, 0, (size_t)NN*16*4, stream);
  hipMemsetAsync(x1, 0, (size_t)NN*80*4, stream);
  hipMemsetAsync(out, 0, 112*sizeof(float), stream);

  k_pack <<<384, 256, 0, stream>>>(w2c, w2f, w2cp, w2fp);
  k_geom <<<(NE+255)/256, 256, 0, stream>>>(pos, esrc, edst, lenb, shb, x0);

  for (long long e0=0; e0<NE; e0+=stripeC){
    long long cnt = NE - e0; if (cnt > stripeC) cnt = stripeC;
    int blks = (int)((cnt+127)/128);
    k_gemm_c<<<blks, 256, 0, stream>>>(lenb, w1c, w2cp, wb, (int)e0);
    k_tp_c  <<<blks*2, 256, 0, stream>>>(esrc, edst, shb, x0, wb, (int)e0, hostCG, x1);
  }

  k_gate <<<(NN+255)/256, 256, 0, stream>>>(x1, xg);

  for (long long e0=0; e0<NE; e0+=stripeF){
    long long cnt = NE - e0; if (cnt > stripeF) cnt = stripeF;
    int blks = (int)((cnt+127)/128);
    k_gemm_f<<<blks, 256, 0, stream>>>(lenb, w1f, w2fp, wb, (int)e0);
    int grid = blks < 1172 ? blks : 1172;
    k_tp_f  <<<grid, 256, 0, stream>>>(esrc, edst, shb, xg, wb, (int)e0, blks, hostCG, batch, out);
  }
}

// Round 6
// 3724.055 us; speedup vs baseline: 1.5753x; 1.5753x over previous
//
#include <hip/hip_runtime.h>
#include <cmath>
#include <complex>
#include <cstring>
#include <cstdint>

#define NN 50000
#define NE 600000

#define ISN 0.51298917604257706f
#define RN  1.4142135623730951f

// ---- CG table offsets (flattened, [d1][d2][d3] row-major) ----
#define CG000 0
#define CG110 1
#define CG220 10
#define CG330 35
#define CG011 84
#define CG101 93
#define CG121 102
#define CG211 147
#define CG231 192
#define CG321 297
#define CG111 402
#define CG221 429
#define CG331 504
#define CGTOT 651

struct CGTab { float v[CGTOT]; };

// ===================== host: real Wigner-3j (mirrors reference) =====================
static double factd(int n){ double r=1.0; for(int i=2;i<=n;++i) r*=(double)i; return r; }

static void cg_complex_h(int j1,int j2,int j3,double* C){
  const int d2=2*j2+1, d3=2*j3+1;
  const int tot=(2*j1+1)*d2*d3;
  for(int i=0;i<tot;++i) C[i]=0.0;
  for(int m1=-j1;m1<=j1;++m1) for(int m2=-j2;m2<=j2;++m2){
    int m3=m1+m2; if(m3<-j3||m3>j3) continue;
    double pref=std::sqrt((double)(2*j3+1)*factd(j3+j1-j2)*factd(j3-j1+j2)*factd(j1+j2-j3)/factd(j1+j2+j3+1));
    pref*=std::sqrt(factd(j3+m3)*factd(j3-m3)*factd(j1-m1)*factd(j1+m1)*factd(j2-m2)*factd(j2+m2));
    double s=0.0;
    for(int k=0;k<=j1+j2-j3;++k){
      int a1=j1+j2-j3-k,a2=j1-m1-k,a3=j2+m2-k,a4=j3-j2+m1+k,a5=j3-j1-m2+k;
      if(a1<0||a2<0||a3<0||a4<0||a5<0) continue;
      double pr=factd(k)*factd(a1)*factd(a2)*factd(a3)*factd(a4)*factd(a5);
      s+=((k&1)?-1.0:1.0)/pr;
    }
    C[(m1+j1)*d2*d3+(m2+j2)*d3+(m3+j3)]=pref*s;
  }
}

typedef std::complex<double> cdbl;

static void real_change_h(int l, cdbl* A){
  int d=2*l+1;
  for(int i=0;i<d*d;++i) A[i]=cdbl(0,0);
  A[l*d+l]=cdbl(1,0);
  const double is2=1.0/std::sqrt(2.0);
  for(int m=1;m<=l;++m){
    double sg=(m&1)?-1.0:1.0;
    A[(l+m)*d+(l-m)]=cdbl(is2,0);
    A[(l+m)*d+(l+m)]=cdbl(sg*is2,0);
    A[(l-m)*d+(l-m)]=cdbl(0,is2);
    A[(l-m)*d+(l+m)]=cdbl(0,-sg*is2);
  }
}

static void real_w3j_h(int l1,int l2,int l3,float* R){
  const int d1=2*l1+1,d2=2*l2+1,d3=2*l3+1;
  double cg[512]; cg_complex_h(l1,l2,l3,cg);
  double w[512];
  for(int a=0;a<d1;++a)for(int b=0;b<d2;++b)for(int m3=-l3;m3<=l3;++m3){
    double sg=((l1-l2-m3)&1)?-1.0:1.0;
    w[a*d2*d3+b*d3+(m3+l3)]=sg/std::sqrt((double)(2*l3+1))*cg[a*d2*d3+b*d3+(-m3+l3)];
  }
  cdbl A1[49],A2[49],A3[49];
  real_change_h(l1,A1); real_change_h(l2,A2); real_change_h(l3,A3);
  double nre=0.0,nim=0.0;
  cdbl T[512];
  for(int i=0;i<d1;++i)for(int j=0;j<d2;++j)for(int k=0;k<d3;++k){
    cdbl s(0,0);
    for(int a=0;a<d1;++a){ cdbl f1=A1[i*d1+a];
      if(f1.real()==0.0&&f1.imag()==0.0) continue;
      for(int b=0;b<d2;++b){ cdbl f2=A2[j*d2+b];
        if(f2.real()==0.0&&f2.imag()==0.0) continue;
        cdbl f12=f1*f2;
        for(int c=0;c<d3;++c){ cdbl f3=A3[k*d3+c];
          if(f3.real()==0.0&&f3.imag()==0.0) continue;
          s+=f12*f3*w[a*d2*d3+b*d3+c];
        }
      }
    }
    T[i*d2*d3+j*d3+k]=s;
    nre+=s.real()*s.real(); nim+=s.imag()*s.imag();
  }
  bool useRe = std::sqrt(nre)>=std::sqrt(nim);
  for(int i=0;i<d1*d2*d3;++i) R[i]=(float)(useRe?T[i].real():T[i].imag());
}

static void build_cg(CGTab& t){
  struct E{int l1,l2,l3,off;};
  const E es[13]={{0,0,0,CG000},{1,1,0,CG110},{2,2,0,CG220},{3,3,0,CG330},
    {0,1,1,CG011},{1,0,1,CG101},{1,2,1,CG121},{2,1,1,CG211},{2,3,1,CG231},
    {3,2,1,CG321},{1,1,1,CG111},{2,2,1,CG221},{3,3,1,CG331}};
  for(int i=0;i<13;++i) real_w3j_h(es[i].l1,es[i].l2,es[i].l3,t.v+es[i].off);
}

// ===================== device helpers =====================
__device__ __forceinline__ void atomicAddF(float* p, float v){
  unsafeAtomicAdd(p, v);
}
__device__ __forceinline__ void ld16f(const float* p, float* d){
  const float4* q=(const float4*)p;
  #pragma unroll
  for(int i=0;i<4;++i){ float4 t=q[i]; d[4*i]=t.x; d[4*i+1]=t.y; d[4*i+2]=t.z; d[4*i+3]=t.w; }
}

// ===================== k_pack =====================
__global__ void k_pack(const float* __restrict__ w2c, const float* __restrict__ w2f,
                       float* __restrict__ w2cp, float* __restrict__ w2fp){
  int idx = blockIdx.x*256 + threadIdx.x;
  const float Sc = (float)(1.4142135623730951/(16.0*sqrt(3.0))/sqrt(3.8));
  const float Sf = (float)(1.4142135623730951/(16.0*sqrt(3.0))/sqrt(3.8)*0.5);
  const float A_ = (float)sqrt(0.5);
  const float B_ = (float)sqrt(1.0/48.0);
  if (idx < 256*224){
    int row=idx/224, c=idx%224;
    float v=0.f;
    if (c<200){
      int oc; float s;
      if (c<128){ oc=c; s=0.5f; }
      else if (c<176){ int p=(c-128)>>3, m=(c-128)&7; oc=128+16*p+m; s=A_; }
      else { int p=(c-176)>>3, m=(c-176)&7; oc=224+16*p+m; s=1.0f; }
      v = w2c[row*272+oc]*(Sc*s);
    }
    w2cp[idx]=v;
  } else {
    idx -= 256*224;
    int row=idx/160, c=idx%160;
    float v=0.f;
    if (c<152){
      int oc; float s;
      if (c<8){ oc=8+c; s=0.25f; }
      else if (c<104){ oc=16+(c-8); s=B_; }
      else { oc=208+(c-104); s=B_; }
      v = w2f[row*304+oc]*(Sf*s);
    }
    w2fp[idx]=v;
  }
}

// ===================== CSR build =====================
__global__ void k_deg(const int* __restrict__ edst, int* __restrict__ deg){
  int e = blockIdx.x*256+threadIdx.x;
  if (e<NE) atomicAdd(&deg[edst[e]], 1);
}

__global__ __launch_bounds__(1024)
void k_scan(const int* __restrict__ deg, int* __restrict__ off, int* __restrict__ cur){
  __shared__ int part[1024];
  const int t=threadIdx.x;
  const int st=t*49, en=(st+49<NN)?(st+49):NN;
  int s=0;
  for(int i=st;i<en;++i) s+=deg[i];
  part[t]=s; __syncthreads();
  for(int d=1;d<1024;d<<=1){
    int v=(t>=d)?part[t-d]:0;
    __syncthreads();
    part[t]+=v;
    __syncthreads();
  }
  int run=part[t]-s;
  for(int i=st;i<en;++i){ off[i]=run; cur[i]=run; run+=deg[i]; }
  if (t==1023) off[NN]=part[1023];
}

// ===================== k_geom: SH + scatter into sorted slots =====================
__global__ void k_geom(const float* __restrict__ pos, const int* __restrict__ esrc,
                       const int* __restrict__ edst, const int* __restrict__ batch,
                       int* __restrict__ cur, float* __restrict__ len_s,
                       float* __restrict__ sh_s, int* __restrict__ src_s,
                       int* __restrict__ bat_s){
  int e = blockIdx.x*256+threadIdx.x;
  if (e>=NE) return;
  int s=esrc[e], d=edst[e];
  float vx=pos[3*s]-pos[3*d], vy=pos[3*s+1]-pos[3*d+1], vz=pos[3*s+2]-pos[3*d+2];
  float len=sqrtf(vx*vx+vy*vy+vz*vz);
  float inv=1.0f/fmaxf(len,1e-9f);
  float x=vx*inv, y=vy*inv, z=vz*inv;
  float x2=x*x, y2=y*y, z2=z*z;
  float sh[16];
  sh[0]=1.0f;
  sh[1]=1.7320508f*y; sh[2]=1.7320508f*z; sh[3]=1.7320508f*x;
  sh[4]=3.8729833f*x*y; sh[5]=3.8729833f*y*z; sh[6]=1.1180340f*(3.0f*z2-1.0f);
  sh[7]=3.8729833f*x*z; sh[8]=1.9364917f*(x2-y2);
  sh[9]=2.0916501f*y*(3.0f*x2-y2); sh[10]=10.2469508f*x*y*z;
  sh[11]=1.6201852f*y*(5.0f*z2-1.0f); sh[12]=1.3228757f*z*(5.0f*z2-3.0f);
  sh[13]=1.6201852f*x*(5.0f*z2-1.0f); sh[14]=5.1234754f*z*(x2-y2);
  sh[15]=2.0916501f*x*(x2-3.0f*y2);
  int p = atomicAdd(&cur[d], 1);
  len_s[p]=len; src_s[p]=s; bat_s[p]=batch[d];
  float4* sp=(float4*)(sh_s+(size_t)16*p);
  sp[0]=make_float4(sh[0],sh[1],sh[2],sh[3]);
  sp[1]=make_float4(sh[4],sh[5],sh[6],sh[7]);
  sp[2]=make_float4(sh[8],sh[9],sh[10],sh[11]);
  sp[3]=make_float4(sh[12],sh[13],sh[14],sh[15]);
}

// ===================== k_gather16: x0[n][ch] = ISN * sum sh_s =====================
__global__ void k_gather16(const int* __restrict__ off, const float* __restrict__ sh_s,
                           float* __restrict__ x0){
  int idx = blockIdx.x*256+threadIdx.x;
  if (idx >= NN*16) return;
  int n = idx>>4, ch = idx&15;
  int a=off[n], b=off[n+1];
  float sum=0.f;
  for(int j=a;j<b;++j) sum += sh_s[(size_t)j*16+ch];
  x0[(size_t)n*16+ch] = sum*ISN;
}

// ===================== k_gemm_c: sorted-edge weights GEMM, 128 x 224 =====================
__global__ __launch_bounds__(256)
void k_gemm_c(const float* __restrict__ len_s, const float* __restrict__ w1,
              const float* __restrict__ w2p, float* __restrict__ wb,
              const int* __restrict__ off, int n0, int n1){
  const int estart=off[n0], eend=off[n1];
  const int ebl = blockIdx.x*128;
  if (estart + ebl >= eend) return;
  __shared__ float hA[32][128];
  __shared__ float w2s[32][224];
  const int tid=threadIdx.x;
  const int sub=tid&7, kk0=tid>>3;
  const int tn=tid&15, tm=tid>>4;

  float em0[16],em1[16],em2[16];
  #pragma unroll
  for(int i=0;i<16;++i){
    int ei = estart + ebl + 16*sub + i;
    float len = (ei<eend)? len_s[ei] : 1.0f;
    float t0=2.0f*(len-1.0f), t1=2.0f*(len-1.5f), t2=2.0f*(len-2.0f);
    em0[i]=expf(-t0*t0)*1.7320508f;
    em1[i]=expf(-t1*t1)*1.7320508f;
    em2[i]=expf(-t2*t2)*1.7320508f;
  }

  float acc[8][14];
  #pragma unroll
  for(int r=0;r<8;++r)
    #pragma unroll
    for(int c=0;c<14;++c) acc[r][c]=0.f;

  for(int kc=0;kc<8;++kc){
    {
      int K=kc*32+kk0;
      float a=w1[K], b=w1[256+K], c=w1[512+K];
      #pragma unroll
      for(int g=0;g<4;++g){
        float h0=fmaxf(em0[4*g+0]*a+em1[4*g+0]*b+em2[4*g+0]*c,0.f);
        float h1=fmaxf(em0[4*g+1]*a+em1[4*g+1]*b+em2[4*g+1]*c,0.f);
        float h2=fmaxf(em0[4*g+2]*a+em1[4*g+2]*b+em2[4*g+2]*c,0.f);
        float h3=fmaxf(em0[4*g+3]*a+em1[4*g+3]*b+em2[4*g+3]*c,0.f);
        *(float4*)&hA[kk0][16*sub+4*g]=make_float4(h0,h1,h2,h3);
      }
    }
    {
      const float4* src=(const float4*)(w2p+(size_t)kc*32*224);
      float4* dst=(float4*)&w2s[0][0];
      #pragma unroll
      for(int i=0;i<7;++i) dst[tid+256*i]=src[tid+256*i];
    }
    __syncthreads();
    #pragma unroll
    for(int kk=0;kk<32;++kk){
      float4 av0=*(const float4*)&hA[kk][8*tm];
      float4 av1=*(const float4*)&hA[kk][8*tm+4];
      float b[14];
      #pragma unroll
      for(int s=0;s<7;++s){ float2 bv=*(const float2*)&w2s[kk][14*tn+2*s]; b[2*s]=bv.x; b[2*s+1]=bv.y; }
      #pragma unroll
      for(int c=0;c<14;++c){
        acc[0][c]+=av0.x*b[c]; acc[1][c]+=av0.y*b[c]; acc[2][c]+=av0.z*b[c]; acc[3][c]+=av0.w*b[c];
        acc[4][c]+=av1.x*b[c]; acc[5][c]+=av1.y*b[c]; acc[6][c]+=av1.z*b[c]; acc[7][c]+=av1.w*b[c];
      }
    }
    __syncthreads();
  }

  #pragma unroll
  for(int r=0;r<8;++r){
    int row = ebl + 8*tm + r;
    if (estart + row < eend){
      float* prow = wb + (size_t)row*224 + 14*tn;
      #pragma unroll
      for(int s=0;s<7;++s) *(float2*)&prow[2*s]=make_float2(acc[r][2*s],acc[r][2*s+1]);
    }
  }
}

// ===================== k_tp_c: sorted-edge TP -> dense ef1[edge][80] (NO atomics) =====================
__global__ __launch_bounds__(256)
void k_tp_c(const int* __restrict__ src_s, const float* __restrict__ sh_s,
            const float* __restrict__ x0, const float* __restrict__ wb,
            float* __restrict__ ef1, const int* __restrict__ off,
            int n0, int n1, CGTab cgt){
  const int estart=off[n0], eend=off[n1];
  const int base = estart + blockIdx.x*64;
  if (base >= eend) return;
  __shared__ float sh8[64][9];
  __shared__ float sh1o[64][25];
  __shared__ float shX[64][9];
  const int tid=threadIdx.x, wv=tid>>6, lane=tid&63;
  const int i = base + lane;
  const int el = blockIdx.x*64 + lane;
  const bool alive = (i < eend);
  float efA[24], efX[8];
  #pragma unroll
  for(int k=0;k<24;++k) efA[k]=0.f;
  #pragma unroll
  for(int k=0;k<8;++k) efX[k]=0.f;

  if (alive){
    int srcn=src_s[i];
    float s1[16], s2[16];
    ld16f(x0+(size_t)16*srcn, s1);
    ld16f(sh_s+(size_t)16*i, s2);
    const float* wr = wb + (size_t)el*224 + 56*wv;

    if (wv<=2){
      float T[4];
      T[0]=s1[0]*s2[0]*cgt.v[CG000];
      T[1]=0.f;
      #pragma unroll
      for(int a=0;a<3;++a)
        #pragma unroll
        for(int b=0;b<3;++b) T[1]+=s1[1+a]*s2[1+b]*cgt.v[CG110+3*a+b];
      T[2]=0.f;
      #pragma unroll
      for(int a=0;a<5;++a)
        #pragma unroll
        for(int b=0;b<5;++b) T[2]+=s1[4+a]*s2[4+b]*cgt.v[CG220+5*a+b];
      T[3]=0.f;
      #pragma unroll
      for(int a=0;a<7;++a)
        #pragma unroll
        for(int b=0;b<7;++b) T[3]+=s1[9+a]*s2[9+b]*cgt.v[CG330+7*a+b];

      if (wv==0){
        #pragma unroll
        for(int q=0;q<14;++q){
          float4 w4=((const float4*)wr)[q];
          float wa[4]={w4.x,w4.y,w4.z,w4.w};
          #pragma unroll
          for(int t=0;t<4;++t){ int c=4*q+t; efA[c&15]+=wa[t]*T[c>>4]; }
        }
      } else if (wv==1){
        float ef8[8];
        #pragma unroll
        for(int k=0;k<8;++k) ef8[k]=0.f;
        #pragma unroll
        for(int q=0;q<14;++q){
          float4 w4=((const float4*)wr)[q];
          float wa[4]={w4.x,w4.y,w4.z,w4.w};
          #pragma unroll
          for(int t=0;t<4;++t){
            int c=4*q+t;
            if (c<8)        ef8[c]        += wa[t]*T[3];
            else if (c<40)  efA[(c-8)&7]  += wa[t]*T[(c-8)>>3];
            else            efX[(c-40)&7] += wa[t]*T[(c-40)>>3];
          }
        }
        #pragma unroll
        for(int k=0;k<8;++k) sh8[lane][k]=ef8[k];
        #pragma unroll
        for(int k=0;k<8;++k) shX[lane][k]=efX[k];
      } else {
        float T1o[5][3];
        #pragma unroll
        for(int p=0;p<5;++p)
          #pragma unroll
          for(int k=0;k<3;++k) T1o[p][k]=0.f;
        #pragma unroll
        for(int b=0;b<3;++b){ float pr=s1[0]*s2[1+b];
          #pragma unroll
          for(int k=0;k<3;++k) T1o[0][k]+=pr*cgt.v[CG011+3*b+k]; }
        #pragma unroll
        for(int a=0;a<3;++a){ float pr=s1[1+a]*s2[0];
          #pragma unroll
          for(int k=0;k<3;++k) T1o[1][k]+=pr*cgt.v[CG101+3*a+k]; }
        #pragma unroll
        for(int a=0;a<3;++a)
          #pragma unroll
          for(int b=0;b<5;++b){ float pr=s1[1+a]*s2[4+b];
            #pragma unroll
            for(int k=0;k<3;++k) T1o[2][k]+=pr*cgt.v[CG121+(5*a+b)*3+k]; }
        #pragma unroll
        for(int a=0;a<5;++a)
          #pragma unroll
          for(int b=0;b<3;++b){ float pr=s1[4+a]*s2[1+b];
            #pragma unroll
            for(int k=0;k<3;++k) T1o[3][k]+=pr*cgt.v[CG211+(3*a+b)*3+k]; }
        #pragma unroll
        for(int a=0;a<5;++a)
          #pragma unroll
          for(int b=0;b<7;++b){ float pr=s1[4+a]*s2[9+b];
            #pragma unroll
            for(int k=0;k<3;++k) T1o[4][k]+=pr*cgt.v[CG231+(7*a+b)*3+k]; }
        #pragma unroll
        for(int q=0;q<14;++q){
          float4 w4=((const float4*)wr)[q];
          float wa[4]={w4.x,w4.y,w4.z,w4.w};
          #pragma unroll
          for(int t=0;t<4;++t){
            int c=4*q+t;
            if (c<16){
              efX[c&7] += wa[t]*T[2+(c>>3)];
            } else {
              int loc=c-16; int p=loc>>3, m=loc&7;
              #pragma unroll
              for(int k=0;k<3;++k) efA[3*m+k]+=wa[t]*T1o[p][k];
            }
          }
        }
      }
    } else {
      float T321[3]={0.f,0.f,0.f};
      #pragma unroll
      for(int a=0;a<7;++a)
        #pragma unroll
        for(int b=0;b<5;++b){ float pr=s1[9+a]*s2[4+b];
          #pragma unroll
          for(int k=0;k<3;++k) T321[k]+=pr*cgt.v[CG321+(5*a+b)*3+k]; }
      float T1e[3][3];
      #pragma unroll
      for(int p=0;p<3;++p)
        #pragma unroll
        for(int k=0;k<3;++k) T1e[p][k]=0.f;
      #pragma unroll
      for(int a=0;a<3;++a)
        #pragma unroll
        for(int b=0;b<3;++b){ float pr=s1[1+a]*s2[1+b];
          #pragma unroll
          for(int k=0;k<3;++k) T1e[0][k]+=pr*cgt.v[CG111+(3*a+b)*3+k]; }
      #pragma unroll
      for(int a=0;a<5;++a)
        #pragma unroll
        for(int b=0;b<5;++b){ float pr=s1[4+a]*s2[4+b];
          #pragma unroll
          for(int k=0;k<3;++k) T1e[1][k]+=pr*cgt.v[CG221+(5*a+b)*3+k]; }
      #pragma unroll
      for(int a=0;a<7;++a)
        #pragma unroll
        for(int b=0;b<7;++b){ float pr=s1[9+a]*s2[9+b];
          #pragma unroll
          for(int k=0;k<3;++k) T1e[2][k]+=pr*cgt.v[CG331+(7*a+b)*3+k]; }
      #pragma unroll
      for(int q=0;q<8;++q){
        float4 w4=((const float4*)wr)[q];
        float wa[4]={w4.x,w4.y,w4.z,w4.w};
        #pragma unroll
        for(int t=0;t<4;++t){
          int c=4*q+t;
          if (c<8){
            #pragma unroll
            for(int k=0;k<3;++k) sh1o[lane][3*c+k]=wa[t]*T321[k];
          } else {
            int loc2=c-8; int p=loc2>>3, m=loc2&7;
            #pragma unroll
            for(int k=0;k<3;++k) efA[3*m+k]+=wa[t]*T1e[p][k];
          }
        }
      }
    }
  }
  __syncthreads();
  if (alive){
    float* orow = ef1 + (size_t)el*80;
    if (wv==0){
      #pragma unroll
      for(int k=0;k<8;++k) efA[8+k]+=sh8[lane][k];
      #pragma unroll
      for(int q=0;q<4;++q)
        *(float4*)&orow[4*q]=make_float4(efA[4*q],efA[4*q+1],efA[4*q+2],efA[4*q+3]);
    } else if (wv==1){
      *(float4*)&orow[16]=make_float4(efA[0],efA[1],efA[2],efA[3]);
      *(float4*)&orow[20]=make_float4(efA[4],efA[5],efA[6],efA[7]);
    } else if (wv==2){
      #pragma unroll
      for(int k=0;k<8;++k) efX[k]+=shX[lane][k];
      *(float4*)&orow[24]=make_float4(efX[0],efX[1],efX[2],efX[3]);
      *(float4*)&orow[28]=make_float4(efX[4],efX[5],efX[6],efX[7]);
      #pragma unroll
      for(int k=0;k<24;++k) efA[k]+=sh1o[lane][k];
      #pragma unroll
      for(int q=0;q<6;++q)
        *(float4*)&orow[32+4*q]=make_float4(efA[4*q],efA[4*q+1],efA[4*q+2],efA[4*q+3]);
    } else {
      #pragma unroll
      for(int q=0;q<6;++q)
        *(float4*)&orow[56+4*q]=make_float4(efA[4*q],efA[4*q+1],efA[4*q+2],efA[4*q+3]);
    }
  }
}

// ===================== k_gather80: x1[n][80] = sum ef1 rows (contiguous) =====================
__global__ void k_gather80(const int* __restrict__ off, const float* __restrict__ ef1,
                           float* __restrict__ x1, int n0, int nb){
  int idx = blockIdx.x*256+threadIdx.x;
  if (idx >= nb*80) return;
  int n = n0 + idx/80, ch = idx%80;
  int base = off[n0];
  int a=off[n], b=off[n+1];
  float sum=0.f;
  for(int j=a;j<b;++j) sum += ef1[(size_t)(j-base)*80+ch];
  x1[(size_t)n*80+ch] = sum;
}

// ===================== k_gate =====================
__global__ void k_gate(const float* __restrict__ x1, float* __restrict__ xg){
  int n=blockIdx.x*256+threadIdx.x;
  if (n>=NN) return;
  float v[80];
  const float4* p=(const float4*)(x1+(size_t)80*n);
  #pragma unroll
  for(int i=0;i<20;++i){ float4 q=p[i]; v[4*i]=q.x; v[4*i+1]=q.y; v[4*i+2]=q.z; v[4*i+3]=q.w; }
  float o[64];
  #pragma unroll
  for(int i=0;i<16;++i) o[i]=fmaxf(v[i],0.f)*RN;
  #pragma unroll
  for(int r=0;r<8;++r){ float g=fmaxf(v[16+r],0.f)*RN;
    #pragma unroll
    for(int k=0;k<3;++k) o[16+3*r+k]=v[32+3*r+k]*g; }
  #pragma unroll
  for(int r=0;r<8;++r){ float g=fmaxf(v[24+r],0.f)*RN;
    #pragma unroll
    for(int k=0;k<3;++k) o[40+3*r+k]=v[56+3*r+k]*g; }
  float4* q=(float4*)(xg+(size_t)64*n);
  #pragma unroll
  for(int i=0;i<16;++i) q[i]=make_float4(o[4*i],o[4*i+1],o[4*i+2],o[4*i+3]);
}

// ===================== k_gemm_f: 128 x 160 =====================
__global__ __launch_bounds__(256)
void k_gemm_f(const float* __restrict__ len_s, const float* __restrict__ w1,
              const float* __restrict__ w2p, float* __restrict__ wb,
              const int* __restrict__ off, int n0, int n1){
  const int estart=off[n0], eend=off[n1];
  const int ebl = blockIdx.x*128;
  if (estart + ebl >= eend) return;
  __shared__ float hA[32][128];
  __shared__ float w2s[32][160];
  const int tid=threadIdx.x;
  const int sub=tid&7, kk0=tid>>3;
  const int tn=tid&15, tm=tid>>4;

  float em0[16],em1[16],em2[16];
  #pragma unroll
  for(int i=0;i<16;++i){
    int ei = estart + ebl + 16*sub + i;
    float len = (ei<eend)? len_s[ei] : 1.0f;
    float t0=2.0f*(len-1.0f), t1=2.0f*(len-1.5f), t2=2.0f*(len-2.0f);
    em0[i]=expf(-t0*t0)*1.7320508f;
    em1[i]=expf(-t1*t1)*1.7320508f;
    em2[i]=expf(-t2*t2)*1.7320508f;
  }

  float acc[8][10];
  #pragma unroll
  for(int r=0;r<8;++r)
    #pragma unroll
    for(int c=0;c<10;++c) acc[r][c]=0.f;

  for(int kc=0;kc<8;++kc){
    {
      int K=kc*32+kk0;
      float a=w1[K], b=w1[256+K], c=w1[512+K];
      #pragma unroll
      for(int g=0;g<4;++g){
        float h0=fmaxf(em0[4*g+0]*a+em1[4*g+0]*b+em2[4*g+0]*c,0.f);
        float h1=fmaxf(em0[4*g+1]*a+em1[4*g+1]*b+em2[4*g+1]*c,0.f);
        float h2=fmaxf(em0[4*g+2]*a+em1[4*g+2]*b+em2[4*g+2]*c,0.f);
        float h3=fmaxf(em0[4*g+3]*a+em1[4*g+3]*b+em2[4*g+3]*c,0.f);
        *(float4*)&hA[kk0][16*sub+4*g]=make_float4(h0,h1,h2,h3);
      }
    }
    {
      const float4* src=(const float4*)(w2p+(size_t)kc*32*160);
      float4* dst=(float4*)&w2s[0][0];
      #pragma unroll
      for(int i=0;i<5;++i) dst[tid+256*i]=src[tid+256*i];
    }
    __syncthreads();
    #pragma unroll
    for(int kk=0;kk<32;++kk){
      float4 av0=*(const float4*)&hA[kk][8*tm];
      float4 av1=*(const float4*)&hA[kk][8*tm+4];
      float b[10];
      #pragma unroll
      for(int s=0;s<5;++s){ float2 bv=*(const float2*)&w2s[kk][10*tn+2*s]; b[2*s]=bv.x; b[2*s+1]=bv.y; }
      #pragma unroll
      for(int c=0;c<10;++c){
        acc[0][c]+=av0.x*b[c]; acc[1][c]+=av0.y*b[c]; acc[2][c]+=av0.z*b[c]; acc[3][c]+=av0.w*b[c];
        acc[4][c]+=av1.x*b[c]; acc[5][c]+=av1.y*b[c]; acc[6][c]+=av1.z*b[c]; acc[7][c]+=av1.w*b[c];
      }
    }
    __syncthreads();
  }

  #pragma unroll
  for(int r=0;r<8;++r){
    int row = ebl + 8*tm + r;
    if (estart + row < eend){
      float* prow = wb + (size_t)row*160 + 10*tn;
      #pragma unroll
      for(int s=0;s<5;++s) *(float2*)&prow[2*s]=make_float2(acc[r][2*s],acc[r][2*s+1]);
    }
  }
}

// ===================== k_tp_f: sorted final TP -> graph reduce =====================
__global__ __launch_bounds__(256)
void k_tp_f(const int* __restrict__ src_s, const float* __restrict__ sh_s,
            const float* __restrict__ xg, const float* __restrict__ wb,
            const int* __restrict__ bat_s, const int* __restrict__ off,
            int n0, int n1, CGTab cgt, float* __restrict__ out){
  const int estart=off[n0], eend=off[n1];
  const int base = estart + blockIdx.x*128;
  if (base >= eend) return;
  __shared__ float gacc[16][8];
  const int tid=threadIdx.x;
  if (tid<128) ((float*)gacc)[tid]=0.f;
  __syncthreads();
  const int lane=tid&63, wv=tid>>6;
  const int q=wv&1, half=wv>>1;
  const int i = base + half*64 + lane;
  if (i < eend){
    const int el = blockIdx.x*128 + half*64 + lane;
    int srcn=src_s[i];
    int gidx=bat_s[i];
    const float* yp = xg + (size_t)64*srcn;
    float4 s4=*(const float4*)(sh_s+(size_t)16*i);
    float c000=cgt.v[CG000];
    const float* wr = wb + (size_t)el*160;
    float ef[7]={0.f,0.f,0.f,0.f,0.f,0.f,0.f};
    if (q==0){
      float y0[12];
      { const float4* p=(const float4*)yp;
        #pragma unroll
        for(int k=0;k<3;++k){ float4 t=p[k]; y0[4*k]=t.x; y0[4*k+1]=t.y; y0[4*k+2]=t.z; y0[4*k+3]=t.w; } }
      float yA[24];
      { const float4* p=(const float4*)(yp+40);
        #pragma unroll
        for(int k=0;k<6;++k){ float4 t=p[k]; yA[4*k]=t.x; yA[4*k+1]=t.y; yA[4*k+2]=t.z; yA[4*k+3]=t.w; } }
      float du[12];
      #pragma unroll
      for(int u=0;u<12;++u) du[u]=y0[u]*s4.x*c000;
      float shv[3]={s4.y,s4.z,s4.w};
      float tA[8];
      #pragma unroll
      for(int u=0;u<8;++u){
        float sa=0.f;
        #pragma unroll
        for(int a=0;a<3;++a)
          #pragma unroll
          for(int b=0;b<3;++b) sa+=yA[3*u+a]*shv[b]*cgt.v[CG110+3*a+b];
        tA[u]=sa;
      }
      #pragma unroll
      for(int k=0;k<20;++k){
        float4 w4=((const float4*)wr)[k];
        float wa[4]={w4.x,w4.y,w4.z,w4.w};
        #pragma unroll
        for(int t=0;t<4;++t){
          int c=4*k+t;
          if (c<8) ef[0]+=wa[t]*tA[c];
          else { int loc=c-8; ef[1+loc%6]+=wa[t]*du[loc/6]; }
        }
      }
    } else {
      float y1[4];
      { float4 t=*(const float4*)(yp+12); y1[0]=t.x;y1[1]=t.y;y1[2]=t.z;y1[3]=t.w; }
      float yC[24];
      { const float4* p=(const float4*)(yp+16);
        #pragma unroll
        for(int k=0;k<6;++k){ float4 t=p[k]; yC[4*k]=t.x; yC[4*k+1]=t.y; yC[4*k+2]=t.z; yC[4*k+3]=t.w; } }
      float du2[4];
      #pragma unroll
      for(int u=0;u<4;++u) du2[u]=y1[u]*s4.x*c000;
      float shv[3]={s4.y,s4.z,s4.w};
      float tC[8];
      #pragma unroll
      for(int u=0;u<8;++u){
        float sc=0.f;
        #pragma unroll
        for(int a=0;a<3;++a)
          #pragma unroll
          for(int b=0;b<3;++b) sc+=yC[3*u+a]*shv[b]*cgt.v[CG110+3*a+b];
        tC[u]=sc;
      }
      const float4* wr4=(const float4*)(wr+80);
      #pragma unroll
      for(int k=0;k<18;++k){
        float4 w4=wr4[k];
        float wa[4]={w4.x,w4.y,w4.z,w4.w};
        #pragma unroll
        for(int t=0;t<4;++t){
          int c=80+4*k+t;
          if (c<104){ int loc=c-8; ef[1+loc%6]+=wa[t]*du2[loc/6-12]; }
          else { int loc2=c-104; ef[1+loc2%6]+=wa[t]*tC[loc2/6]; }
        }
      }
    }
    #pragma unroll
    for(int oc=0;oc<7;++oc) atomicAdd(&gacc[gidx][oc], ef[oc]);
  }
  __syncthreads();
  if (tid<112) atomicAddF(out+tid, gacc[tid/7][tid%7]);
}

// ===================== launch =====================
extern "C" void kernel_launch(void* const* d_in, const int* in_sizes, int n_in,
                              void* d_out, int out_size, void* d_ws, size_t ws_size,
                              hipStream_t stream) {
  (void)in_sizes; (void)n_in; (void)out_size;
  const float* pos  = (const float*)d_in[0];
  const int*   batch= (const int*)d_in[1];
  const int*   esrc = (const int*)d_in[2];
  const int*   edst = (const int*)d_in[3];
  const float* w1c  = (const float*)d_in[4];
  const float* w2c  = (const float*)d_in[5];
  const float* w1f  = (const float*)d_in[6];
  const float* w2f  = (const float*)d_in[7];
  float* out = (float*)d_out;
  char* ws = (char*)d_ws;

  const size_t OFF_W2CP = 0;          // 229376
  const size_t OFF_W2FP = 229376;     // 163840 -> 393216
  const size_t OFF_DEG  = 393216;     // 200000 -> 593216
  const size_t OFF_OFF  = 593216;     // 200064 -> 793280
  const size_t OFF_CUR  = 793280;     // 200000 -> 993280
  const size_t OFF_LENS = 993280;     // 2400000 -> 3393280
  const size_t OFF_SRCS = 3393280;    // 2400000 -> 5793280
  const size_t OFF_BATS = 5793280;    // 2400000 -> 8193280
  const size_t OFF_SHS  = 8193280;    // 38400000 -> 46593280
  const size_t OFF_X0   = 46593280;   // 3200000 -> 49793280
  const size_t OFF_X1   = 49793280;   // 16000000 -> 65793280
  const size_t OFF_XG   = 65793280;   // 12800000 -> 78593280
  const size_t OFF_EF   = 78593280;   // capr*320 ; wb follows

  float* w2cp=(float*)(ws+OFF_W2CP);
  float* w2fp=(float*)(ws+OFF_W2FP);
  int*   deg =(int*)(ws+OFF_DEG);
  int*   offp=(int*)(ws+OFF_OFF);
  int*   cur =(int*)(ws+OFF_CUR);
  float* lens=(float*)(ws+OFF_LENS);
  int*   srcs=(int*)(ws+OFF_SRCS);
  int*   bats=(int*)(ws+OFF_BATS);
  float* shs =(float*)(ws+OFF_SHS);
  float* x0  =(float*)(ws+OFF_X0);
  float* x1  =(float*)(ws+OFF_X1);
  float* xg  =(float*)(ws+OFF_XG);

  // stripe capacity from constant ws_size (capture-safe)
  long long capr = 0;
  if (ws_size > OFF_EF) capr = (long long)((ws_size - OFF_EF) / 1216);  // 320(ef)+896(wb) bytes/edge
  capr = (capr/128)*128;
  if (capr > 66048) capr = 66048;
  if (capr < 128) capr = 128;
  float* ef1 = (float*)(ws + OFF_EF);
  float* wb  = (float*)(ws + OFF_EF + (size_t)capr*320);

  // number of node-stripes: expected edges/stripe * 1.25 + 1024 must fit capr
  int nstr = 10;
  while (nstr < 200){
    long long nb = (NN + nstr - 1)/nstr;
    long long expect = nb*12;
    if (expect + expect/4 + 1024 <= capr) break;
    nstr++;
  }
  int NB = (NN + nstr - 1)/nstr;
  int gemmBlks = (int)(capr/128);
  int tpcBlks  = (int)(capr/64);

  static CGTab hostCG;
  build_cg(hostCG);

  hipMemsetAsync(deg, 0, (size_t)NN*4, stream);
  hipMemsetAsync(out, 0, 112*sizeof(float), stream);

  k_pack <<<384, 256, 0, stream>>>(w2c, w2f, w2cp, w2fp);
  k_deg  <<<(NE+255)/256, 256, 0, stream>>>(edst, deg);
  k_scan <<<1, 1024, 0, stream>>>(deg, offp, cur);
  k_geom <<<(NE+255)/256, 256, 0, stream>>>(pos, esrc, edst, batch, cur, lens, shs, srcs, bats);
  k_gather16<<<(NN*16+255)/256, 256, 0, stream>>>(offp, shs, x0);

  for (int s=0; s<nstr; ++s){
    int n0 = s*NB, n1 = n0+NB; if (n1>NN) n1=NN;
    if (n0>=NN) break;
    int nb = n1-n0;
    k_gemm_c<<<gemmBlks, 256, 0, stream>>>(lens, w1c, w2cp, wb, offp, n0, n1);
    k_tp_c  <<<tpcBlks, 256, 0, stream>>>(srcs, shs, x0, wb, ef1, offp, n0, n1, hostCG);
    k_gather80<<<(nb*80+255)/256, 256, 0, stream>>>(offp, ef1, x1, n0, nb);
  }

  k_gate <<<(NN+255)/256, 256, 0, stream>>>(x1, xg);

  for (int s=0; s<nstr; ++s){
    int n0 = s*NB, n1 = n0+NB; if (n1>NN) n1=NN;
    if (n0>=NN) break;
    k_gemm_f<<<gemmBlks, 256, 0, stream>>>(lens, w1f, w2fp, wb, offp, n0, n1);
    k_tp_f  <<<gemmBlks, 256, 0, stream>>>(srcs, shs, xg, wb, bats, offp, n0, n1, hostCG, out);
  }
}

// Round 7
// 966.074 us; speedup vs baseline: 6.0724x; 3.8548x over previous
//
#include <hip/hip_runtime.h>
#include <cmath>
#include <complex>
#include <cstring>
#include <cstdint>

#define NN 50000
#define NE 600000

#define ISN 0.51298917604257706f
#define RN  1.4142135623730951f

// weight-table config: bins at len = i*TDLT, i in [0,TB); LMAX = 4.5
#define TB 4096
#define TINV 910.0f            // (TB-1)/4.5
#define TDLT (4.5f/4095.0f)

// ---- CG table offsets (flattened, [d1][d2][d3] row-major) ----
#define CG000 0
#define CG110 1
#define CG220 10
#define CG330 35
#define CG011 84
#define CG101 93
#define CG121 102
#define CG211 147
#define CG231 192
#define CG321 297
#define CG111 402
#define CG221 429
#define CG331 504
#define CGTOT 651

struct CGTab { float v[CGTOT]; };

// ===================== host: real Wigner-3j (mirrors reference) =====================
static double factd(int n){ double r=1.0; for(int i=2;i<=n;++i) r*=(double)i; return r; }

static void cg_complex_h(int j1,int j2,int j3,double* C){
  const int d2=2*j2+1, d3=2*j3+1;
  const int tot=(2*j1+1)*d2*d3;
  for(int i=0;i<tot;++i) C[i]=0.0;
  for(int m1=-j1;m1<=j1;++m1) for(int m2=-j2;m2<=j2;++m2){
    int m3=m1+m2; if(m3<-j3||m3>j3) continue;
    double pref=std::sqrt((double)(2*j3+1)*factd(j3+j1-j2)*factd(j3-j1+j2)*factd(j1+j2-j3)/factd(j1+j2+j3+1));
    pref*=std::sqrt(factd(j3+m3)*factd(j3-m3)*factd(j1-m1)*factd(j1+m1)*factd(j2-m2)*factd(j2+m2));
    double s=0.0;
    for(int k=0;k<=j1+j2-j3;++k){
      int a1=j1+j2-j3-k,a2=j1-m1-k,a3=j2+m2-k,a4=j3-j2+m1+k,a5=j3-j1-m2+k;
      if(a1<0||a2<0||a3<0||a4<0||a5<0) continue;
      double pr=factd(k)*factd(a1)*factd(a2)*factd(a3)*factd(a4)*factd(a5);
      s+=((k&1)?-1.0:1.0)/pr;
    }
    C[(m1+j1)*d2*d3+(m2+j2)*d3+(m3+j3)]=pref*s;
  }
}

typedef std::complex<double> cdbl;

static void real_change_h(int l, cdbl* A){
  int d=2*l+1;
  for(int i=0;i<d*d;++i) A[i]=cdbl(0,0);
  A[l*d+l]=cdbl(1,0);
  const double is2=1.0/std::sqrt(2.0);
  for(int m=1;m<=l;++m){
    double sg=(m&1)?-1.0:1.0;
    A[(l+m)*d+(l-m)]=cdbl(is2,0);
    A[(l+m)*d+(l+m)]=cdbl(sg*is2,0);
    A[(l-m)*d+(l-m)]=cdbl(0,is2);
    A[(l-m)*d+(l+m)]=cdbl(0,-sg*is2);
  }
}

static void real_w3j_h(int l1,int l2,int l3,float* R){
  const int d1=2*l1+1,d2=2*l2+1,d3=2*l3+1;
  double cg[512]; cg_complex_h(l1,l2,l3,cg);
  double w[512];
  for(int a=0;a<d1;++a)for(int b=0;b<d2;++b)for(int m3=-l3;m3<=l3;++m3){
    double sg=((l1-l2-m3)&1)?-1.0:1.0;
    w[a*d2*d3+b*d3+(m3+l3)]=sg/std::sqrt((double)(2*l3+1))*cg[a*d2*d3+b*d3+(-m3+l3)];
  }
  cdbl A1[49],A2[49],A3[49];
  real_change_h(l1,A1); real_change_h(l2,A2); real_change_h(l3,A3);
  double nre=0.0,nim=0.0;
  cdbl T[512];
  for(int i=0;i<d1;++i)for(int j=0;j<d2;++j)for(int k=0;k<d3;++k){
    cdbl s(0,0);
    for(int a=0;a<d1;++a){ cdbl f1=A1[i*d1+a];
      if(f1.real()==0.0&&f1.imag()==0.0) continue;
      for(int b=0;b<d2;++b){ cdbl f2=A2[j*d2+b];
        if(f2.real()==0.0&&f2.imag()==0.0) continue;
        cdbl f12=f1*f2;
        for(int c=0;c<d3;++c){ cdbl f3=A3[k*d3+c];
          if(f3.real()==0.0&&f3.imag()==0.0) continue;
          s+=f12*f3*w[a*d2*d3+b*d3+c];
        }
      }
    }
    T[i*d2*d3+j*d3+k]=s;
    nre+=s.real()*s.real(); nim+=s.imag()*s.imag();
  }
  bool useRe = std::sqrt(nre)>=std::sqrt(nim);
  for(int i=0;i<d1*d2*d3;++i) R[i]=(float)(useRe?T[i].real():T[i].imag());
}

static void build_cg(CGTab& t){
  struct E{int l1,l2,l3,off;};
  const E es[13]={{0,0,0,CG000},{1,1,0,CG110},{2,2,0,CG220},{3,3,0,CG330},
    {0,1,1,CG011},{1,0,1,CG101},{1,2,1,CG121},{2,1,1,CG211},{2,3,1,CG231},
    {3,2,1,CG321},{1,1,1,CG111},{2,2,1,CG221},{3,3,1,CG331}};
  for(int i=0;i<13;++i) real_w3j_h(es[i].l1,es[i].l2,es[i].l3,t.v+es[i].off);
}

// ===================== device helpers =====================
__device__ __forceinline__ void atomicAddF(float* p, float v){
  unsafeAtomicAdd(p, v);
}
__device__ __forceinline__ void ld16f(const float* p, float* d){
  const float4* q=(const float4*)p;
  #pragma unroll
  for(int i=0;i<4;++i){ float4 t=q[i]; d[4*i]=t.x; d[4*i+1]=t.y; d[4*i+2]=t.z; d[4*i+3]=t.w; }
}
__device__ __forceinline__ float4 lerp4(float4 a, float4 b, float f){
  return make_float4(fmaf(f,b.x-a.x,a.x), fmaf(f,b.y-a.y,a.y),
                     fmaf(f,b.z-a.z,a.z), fmaf(f,b.w-a.w,a.w));
}

// ===================== k_pack: gather/prescale live columns of w2c/w2f =====================
__global__ void k_pack(const float* __restrict__ w2c, const float* __restrict__ w2f,
                       float* __restrict__ w2cp, float* __restrict__ w2fp){
  int idx = blockIdx.x*256 + threadIdx.x;
  const float Sc = (float)(1.4142135623730951/(16.0*sqrt(3.0))/sqrt(3.8));
  const float Sf = (float)(1.4142135623730951/(16.0*sqrt(3.0))/sqrt(3.8)*0.5);
  const float A_ = (float)sqrt(0.5);
  const float B_ = (float)sqrt(1.0/48.0);
  if (idx < 256*224){
    int row=idx/224, c=idx%224;
    float v=0.f;
    if (c<200){
      int oc; float s;
      if (c<128){ oc=c; s=0.5f; }
      else if (c<176){ int p=(c-128)>>3, m=(c-128)&7; oc=128+16*p+m; s=A_; }
      else { int p=(c-176)>>3, m=(c-176)&7; oc=224+16*p+m; s=1.0f; }
      v = w2c[row*272+oc]*(Sc*s);
    }
    w2cp[idx]=v;
  } else {
    idx -= 256*224;
    int row=idx/160, c=idx%160;
    float v=0.f;
    if (c<152){
      int oc; float s;
      if (c<8){ oc=8+c; s=0.25f; }
      else if (c<104){ oc=16+(c-8); s=B_; }
      else { oc=208+(c-104); s=B_; }
      v = w2f[row*304+oc]*(Sf*s);
    }
    w2fp[idx]=v;
  }
}

// ===================== k_table: tabulate weight vectors over len =====================
// grid 384 = 12 col-tiles x 32 bin-chunks; tiles 0..6 -> tabC, 7..11 -> tabF
__global__ __launch_bounds__(256)
void k_table(const float* __restrict__ w1c, const float* __restrict__ w2cp,
             const float* __restrict__ w1f, const float* __restrict__ w2fp,
             float* __restrict__ tabC, float* __restrict__ tabF){
  __shared__ float w2s[256][36];
  const int tile = blockIdx.x % 12;
  const int chunk = blockIdx.x / 12;
  const bool isC = tile < 7;
  const float* w1 = isC ? w1c : w1f;
  const float* w2 = isC ? w2cp : w2fp;
  const int LD = isC ? 224 : 160;
  const int c0 = isC ? tile*32 : (tile-7)*32;
  float* tab = isC ? tabC : tabF;
  const int tid=threadIdx.x;
  {
    int cc = tid & 31, k0 = tid >> 5;
    #pragma unroll
    for (int r=0;r<32;++r){
      int k = r*8 + k0;
      w2s[k][cc] = w2[k*LD + c0 + cc];
    }
  }
  __syncthreads();
  const int binl = tid & 127, cg = tid >> 7;
  const int bin = chunk*128 + binl;
  float len = (float)bin * TDLT;
  float t0=2.0f*(len-1.0f), t1=2.0f*(len-1.5f), t2=2.0f*(len-2.0f);
  float e0=expf(-t0*t0)*1.7320508f;
  float e1=expf(-t1*t1)*1.7320508f;
  float e2=expf(-t2*t2)*1.7320508f;
  float acc[16];
  #pragma unroll
  for(int j=0;j<16;++j) acc[j]=0.f;
  for(int k=0;k<256;++k){
    float h = fmaxf(e0*w1[k]+e1*w1[256+k]+e2*w1[512+k], 0.f);
    const float4* row=(const float4*)&w2s[k][cg*16];
    #pragma unroll
    for(int q=0;q<4;++q){
      float4 wv=row[q];
      acc[4*q]  +=h*wv.x; acc[4*q+1]+=h*wv.y; acc[4*q+2]+=h*wv.z; acc[4*q+3]+=h*wv.w;
    }
  }
  float* orow = tab + (size_t)bin*LD + c0 + cg*16;
  #pragma unroll
  for(int q=0;q<4;++q)
    *(float4*)&orow[4*q]=make_float4(acc[4*q],acc[4*q+1],acc[4*q+2],acc[4*q+3]);
}

// ===================== CSR build =====================
__global__ void k_deg(const int* __restrict__ edst, int* __restrict__ deg){
  int e = blockIdx.x*256+threadIdx.x;
  if (e<NE) atomicAdd(&deg[edst[e]], 1);
}

__global__ __launch_bounds__(1024)
void k_scan(const int* __restrict__ deg, int* __restrict__ off, int* __restrict__ cur){
  __shared__ int part[1024];
  const int t=threadIdx.x;
  const int st=t*49, en=(st+49<NN)?(st+49):NN;
  int s=0;
  for(int i=st;i<en;++i) s+=deg[i];
  part[t]=s; __syncthreads();
  for(int d=1;d<1024;d<<=1){
    int v=(t>=d)?part[t-d]:0;
    __syncthreads();
    part[t]+=v;
    __syncthreads();
  }
  int run=part[t]-s;
  for(int i=st;i<en;++i){ off[i]=run; cur[i]=run; run+=deg[i]; }
  if (t==1023) off[NN]=part[1023];
}

// ===================== k_geom: SH + scatter into sorted slots =====================
__global__ void k_geom(const float* __restrict__ pos, const int* __restrict__ esrc,
                       const int* __restrict__ edst, const int* __restrict__ batch,
                       int* __restrict__ cur, float* __restrict__ len_s,
                       float* __restrict__ sh_s, int* __restrict__ src_s,
                       int* __restrict__ bat_s){
  int e = blockIdx.x*256+threadIdx.x;
  if (e>=NE) return;
  int s=esrc[e], d=edst[e];
  float vx=pos[3*s]-pos[3*d], vy=pos[3*s+1]-pos[3*d+1], vz=pos[3*s+2]-pos[3*d+2];
  float len=sqrtf(vx*vx+vy*vy+vz*vz);
  float inv=1.0f/fmaxf(len,1e-9f);
  float x=vx*inv, y=vy*inv, z=vz*inv;
  float x2=x*x, y2=y*y, z2=z*z;
  float sh[16];
  sh[0]=1.0f;
  sh[1]=1.7320508f*y; sh[2]=1.7320508f*z; sh[3]=1.7320508f*x;
  sh[4]=3.8729833f*x*y; sh[5]=3.8729833f*y*z; sh[6]=1.1180340f*(3.0f*z2-1.0f);
  sh[7]=3.8729833f*x*z; sh[8]=1.9364917f*(x2-y2);
  sh[9]=2.0916501f*y*(3.0f*x2-y2); sh[10]=10.2469508f*x*y*z;
  sh[11]=1.6201852f*y*(5.0f*z2-1.0f); sh[12]=1.3228757f*z*(5.0f*z2-3.0f);
  sh[13]=1.6201852f*x*(5.0f*z2-1.0f); sh[14]=5.1234754f*z*(x2-y2);
  sh[15]=2.0916501f*x*(x2-3.0f*y2);
  int p = atomicAdd(&cur[d], 1);
  len_s[p]=len; src_s[p]=s; bat_s[p]=batch[d];
  float4* sp=(float4*)(sh_s+(size_t)16*p);
  sp[0]=make_float4(sh[0],sh[1],sh[2],sh[3]);
  sp[1]=make_float4(sh[4],sh[5],sh[6],sh[7]);
  sp[2]=make_float4(sh[8],sh[9],sh[10],sh[11]);
  sp[3]=make_float4(sh[12],sh[13],sh[14],sh[15]);
}

// ===================== k_gather16 =====================
__global__ void k_gather16(const int* __restrict__ off, const float* __restrict__ sh_s,
                           float* __restrict__ x0){
  int idx = blockIdx.x*256+threadIdx.x;
  if (idx >= NN*16) return;
  int n = idx>>4, ch = idx&15;
  int a=off[n], b=off[n+1];
  float sum=0.f;
  for(int j=a;j<b;++j) sum += sh_s[(size_t)j*16+ch];
  x0[(size_t)n*16+ch] = sum*ISN;
}

// ===================== k_tp_c: interpolated weights + TP -> dense ef1[edge][80] =====================
__global__ __launch_bounds__(256)
void k_tp_c(const int* __restrict__ src_s, const float* __restrict__ sh_s,
            const float* __restrict__ len_s, const float* __restrict__ x0,
            const float* __restrict__ tabC, float* __restrict__ ef1,
            const int* __restrict__ off, int n0, int n1, CGTab cgt){
  const int estart=off[n0], eend=off[n1];
  const int base = estart + blockIdx.x*64;
  if (base >= eend) return;
  __shared__ float sh8[64][9];
  __shared__ float sh1o[64][25];
  __shared__ float shX[64][9];
  const int tid=threadIdx.x, wv=tid>>6, lane=tid&63;
  const int i = base + lane;
  const int el = blockIdx.x*64 + lane;
  const bool alive = (i < eend);
  float efA[24], efX[8];
  #pragma unroll
  for(int k=0;k<24;++k) efA[k]=0.f;
  #pragma unroll
  for(int k=0;k<8;++k) efX[k]=0.f;

  if (alive){
    int srcn=src_s[i];
    float s1[16], s2[16];
    ld16f(x0+(size_t)16*srcn, s1);
    ld16f(sh_s+(size_t)16*i, s2);
    // interpolation setup
    float len=len_s[i];
    float t = len*TINV;
    int i0 = (int)t;
    float fr = t - (float)i0;
    float wsc = (i0 <= TB-2) ? 1.f : 0.f;
    if (i0 > TB-2){ i0 = TB-2; fr = 0.f; }
    #pragma unroll
    for(int k=0;k<16;++k) s2[k]*=wsc;
    const float4* A = (const float4*)(tabC + (size_t)i0*224);
    const float4* B = (const float4*)(tabC + (size_t)(i0+1)*224);

    if (wv<=2){
      const float4* Aw = A + 14*wv;
      const float4* Bw = B + 14*wv;
      float T[4];
      T[0]=s1[0]*s2[0]*cgt.v[CG000];
      T[1]=0.f;
      #pragma unroll
      for(int a=0;a<3;++a)
        #pragma unroll
        for(int b=0;b<3;++b) T[1]+=s1[1+a]*s2[1+b]*cgt.v[CG110+3*a+b];
      T[2]=0.f;
      #pragma unroll
      for(int a=0;a<5;++a)
        #pragma unroll
        for(int b=0;b<5;++b) T[2]+=s1[4+a]*s2[4+b]*cgt.v[CG220+5*a+b];
      T[3]=0.f;
      #pragma unroll
      for(int a=0;a<7;++a)
        #pragma unroll
        for(int b=0;b<7;++b) T[3]+=s1[9+a]*s2[9+b]*cgt.v[CG330+7*a+b];

      if (wv==0){
        #pragma unroll
        for(int q=0;q<14;++q){
          float4 w4=lerp4(Aw[q],Bw[q],fr);
          float wa[4]={w4.x,w4.y,w4.z,w4.w};
          #pragma unroll
          for(int t4=0;t4<4;++t4){ int c=4*q+t4; efA[c&15]+=wa[t4]*T[c>>4]; }
        }
      } else if (wv==1){
        float ef8[8];
        #pragma unroll
        for(int k=0;k<8;++k) ef8[k]=0.f;
        #pragma unroll
        for(int q=0;q<14;++q){
          float4 w4=lerp4(Aw[q],Bw[q],fr);
          float wa[4]={w4.x,w4.y,w4.z,w4.w};
          #pragma unroll
          for(int t4=0;t4<4;++t4){
            int c=4*q+t4;
            if (c<8)        ef8[c]        += wa[t4]*T[3];
            else if (c<40)  efA[(c-8)&7]  += wa[t4]*T[(c-8)>>3];
            else            efX[(c-40)&7] += wa[t4]*T[(c-40)>>3];
          }
        }
        #pragma unroll
        for(int k=0;k<8;++k) sh8[lane][k]=ef8[k];
        #pragma unroll
        for(int k=0;k<8;++k) shX[lane][k]=efX[k];
      } else {
        float T1o[5][3];
        #pragma unroll
        for(int p=0;p<5;++p)
          #pragma unroll
          for(int k=0;k<3;++k) T1o[p][k]=0.f;
        #pragma unroll
        for(int b=0;b<3;++b){ float pr=s1[0]*s2[1+b];
          #pragma unroll
          for(int k=0;k<3;++k) T1o[0][k]+=pr*cgt.v[CG011+3*b+k]; }
        #pragma unroll
        for(int a=0;a<3;++a){ float pr=s1[1+a]*s2[0];
          #pragma unroll
          for(int k=0;k<3;++k) T1o[1][k]+=pr*cgt.v[CG101+3*a+k]; }
        #pragma unroll
        for(int a=0;a<3;++a)
          #pragma unroll
          for(int b=0;b<5;++b){ float pr=s1[1+a]*s2[4+b];
            #pragma unroll
            for(int k=0;k<3;++k) T1o[2][k]+=pr*cgt.v[CG121+(5*a+b)*3+k]; }
        #pragma unroll
        for(int a=0;a<5;++a)
          #pragma unroll
          for(int b=0;b<3;++b){ float pr=s1[4+a]*s2[1+b];
            #pragma unroll
            for(int k=0;k<3;++k) T1o[3][k]+=pr*cgt.v[CG211+(3*a+b)*3+k]; }
        #pragma unroll
        for(int a=0;a<5;++a)
          #pragma unroll
          for(int b=0;b<7;++b){ float pr=s1[4+a]*s2[9+b];
            #pragma unroll
            for(int k=0;k<3;++k) T1o[4][k]+=pr*cgt.v[CG231+(7*a+b)*3+k]; }
        #pragma unroll
        for(int q=0;q<14;++q){
          float4 w4=lerp4(Aw[q],Bw[q],fr);
          float wa[4]={w4.x,w4.y,w4.z,w4.w};
          #pragma unroll
          for(int t4=0;t4<4;++t4){
            int c=4*q+t4;
            if (c<16){
              efX[c&7] += wa[t4]*T[2+(c>>3)];
            } else {
              int loc=c-16; int p=loc>>3, m=loc&7;
              #pragma unroll
              for(int k=0;k<3;++k) efA[3*m+k]+=wa[t4]*T1o[p][k];
            }
          }
        }
      }
    } else {
      const float4* Aw = A + 42;
      const float4* Bw = B + 42;
      float T321[3]={0.f,0.f,0.f};
      #pragma unroll
      for(int a=0;a<7;++a)
        #pragma unroll
        for(int b=0;b<5;++b){ float pr=s1[9+a]*s2[4+b];
          #pragma unroll
          for(int k=0;k<3;++k) T321[k]+=pr*cgt.v[CG321+(5*a+b)*3+k]; }
      float T1e[3][3];
      #pragma unroll
      for(int p=0;p<3;++p)
        #pragma unroll
        for(int k=0;k<3;++k) T1e[p][k]=0.f;
      #pragma unroll
      for(int a=0;a<3;++a)
        #pragma unroll
        for(int b=0;b<3;++b){ float pr=s1[1+a]*s2[1+b];
          #pragma unroll
          for(int k=0;k<3;++k) T1e[0][k]+=pr*cgt.v[CG111+(3*a+b)*3+k]; }
      #pragma unroll
      for(int a=0;a<5;++a)
        #pragma unroll
        for(int b=0;b<5;++b){ float pr=s1[4+a]*s2[4+b];
          #pragma unroll
          for(int k=0;k<3;++k) T1e[1][k]+=pr*cgt.v[CG221+(5*a+b)*3+k]; }
      #pragma unroll
      for(int a=0;a<7;++a)
        #pragma unroll
        for(int b=0;b<7;++b){ float pr=s1[9+a]*s2[9+b];
          #pragma unroll
          for(int k=0;k<3;++k) T1e[2][k]+=pr*cgt.v[CG331+(7*a+b)*3+k]; }
      #pragma unroll
      for(int q=0;q<8;++q){
        float4 w4=lerp4(Aw[q],Bw[q],fr);
        float wa[4]={w4.x,w4.y,w4.z,w4.w};
        #pragma unroll
        for(int t4=0;t4<4;++t4){
          int c=4*q+t4;
          if (c<8){
            #pragma unroll
            for(int k=0;k<3;++k) sh1o[lane][3*c+k]=wa[t4]*T321[k];
          } else {
            int loc2=c-8; int p=loc2>>3, m=loc2&7;
            #pragma unroll
            for(int k=0;k<3;++k) efA[3*m+k]+=wa[t4]*T1e[p][k];
          }
        }
      }
    }
  }
  __syncthreads();
  if (alive){
    float* orow = ef1 + (size_t)el*80;
    if (wv==0){
      #pragma unroll
      for(int k=0;k<8;++k) efA[8+k]+=sh8[lane][k];
      #pragma unroll
      for(int q=0;q<4;++q)
        *(float4*)&orow[4*q]=make_float4(efA[4*q],efA[4*q+1],efA[4*q+2],efA[4*q+3]);
    } else if (wv==1){
      *(float4*)&orow[16]=make_float4(efA[0],efA[1],efA[2],efA[3]);
      *(float4*)&orow[20]=make_float4(efA[4],efA[5],efA[6],efA[7]);
    } else if (wv==2){
      #pragma unroll
      for(int k=0;k<8;++k) efX[k]+=shX[lane][k];
      *(float4*)&orow[24]=make_float4(efX[0],efX[1],efX[2],efX[3]);
      *(float4*)&orow[28]=make_float4(efX[4],efX[5],efX[6],efX[7]);
      #pragma unroll
      for(int k=0;k<24;++k) efA[k]+=sh1o[lane][k];
      #pragma unroll
      for(int q=0;q<6;++q)
        *(float4*)&orow[32+4*q]=make_float4(efA[4*q],efA[4*q+1],efA[4*q+2],efA[4*q+3]);
    } else {
      #pragma unroll
      for(int q=0;q<6;++q)
        *(float4*)&orow[56+4*q]=make_float4(efA[4*q],efA[4*q+1],efA[4*q+2],efA[4*q+3]);
    }
  }
}

// ===================== k_gather80 =====================
__global__ void k_gather80(const int* __restrict__ off, const float* __restrict__ ef1,
                           float* __restrict__ x1, int n0, int nb){
  int idx = blockIdx.x*256+threadIdx.x;
  if (idx >= nb*80) return;
  int n = n0 + idx/80, ch = idx%80;
  int base = off[n0];
  int a=off[n], b=off[n+1];
  float sum=0.f;
  for(int j=a;j<b;++j) sum += ef1[(size_t)(j-base)*80+ch];
  x1[(size_t)n*80+ch] = sum;
}

// ===================== k_gate =====================
__global__ void k_gate(const float* __restrict__ x1, float* __restrict__ xg){
  int n=blockIdx.x*256+threadIdx.x;
  if (n>=NN) return;
  float v[80];
  const float4* p=(const float4*)(x1+(size_t)80*n);
  #pragma unroll
  for(int i=0;i<20;++i){ float4 q=p[i]; v[4*i]=q.x; v[4*i+1]=q.y; v[4*i+2]=q.z; v[4*i+3]=q.w; }
  float o[64];
  #pragma unroll
  for(int i=0;i<16;++i) o[i]=fmaxf(v[i],0.f)*RN;
  #pragma unroll
  for(int r=0;r<8;++r){ float g=fmaxf(v[16+r],0.f)*RN;
    #pragma unroll
    for(int k=0;k<3;++k) o[16+3*r+k]=v[32+3*r+k]*g; }
  #pragma unroll
  for(int r=0;r<8;++r){ float g=fmaxf(v[24+r],0.f)*RN;
    #pragma unroll
    for(int k=0;k<3;++k) o[40+3*r+k]=v[56+3*r+k]*g; }
  float4* q=(float4*)(xg+(size_t)64*n);
  #pragma unroll
  for(int i=0;i<16;++i) q[i]=make_float4(o[4*i],o[4*i+1],o[4*i+2],o[4*i+3]);
}

// ===================== k_tp_f: interpolated final TP -> graph reduce (single dispatch) =====================
__global__ __launch_bounds__(256)
void k_tp_f(const int* __restrict__ src_s, const float* __restrict__ sh_s,
            const float* __restrict__ len_s, const float* __restrict__ xg,
            const float* __restrict__ tabF, const int* __restrict__ bat_s,
            CGTab cgt, float* __restrict__ out){
  __shared__ float gacc[16][8];
  const int tid=threadIdx.x;
  if (tid<128) ((float*)gacc)[tid]=0.f;
  __syncthreads();
  const int lane=tid&63, wv=tid>>6;
  const int q=wv&1, half=wv>>1;
  const int wbase = blockIdx.x*128 + half*64;
  if (wbase < NE){                    // whole wave valid (NE multiple of 64)
    const int i = wbase + lane;
    int srcn=src_s[i];
    int gidx=bat_s[i];
    const float* yp = xg + (size_t)64*srcn;
    float4 s4=*(const float4*)(sh_s+(size_t)16*i);
    float len=len_s[i];
    float t = len*TINV;
    int i0 = (int)t;
    float fr = t - (float)i0;
    float wsc = (i0 <= TB-2) ? 1.f : 0.f;
    if (i0 > TB-2){ i0 = TB-2; fr = 0.f; }
    s4.x*=wsc; s4.y*=wsc; s4.z*=wsc; s4.w*=wsc;
    const float4* A = (const float4*)(tabF + (size_t)i0*160);
    const float4* B = (const float4*)(tabF + (size_t)(i0+1)*160);
    float c000=cgt.v[CG000];
    float ef[7]={0.f,0.f,0.f,0.f,0.f,0.f,0.f};
    if (q==0){
      float y0[12];
      { const float4* p=(const float4*)yp;
        #pragma unroll
        for(int k=0;k<3;++k){ float4 tt=p[k]; y0[4*k]=tt.x; y0[4*k+1]=tt.y; y0[4*k+2]=tt.z; y0[4*k+3]=tt.w; } }
      float yA[24];
      { const float4* p=(const float4*)(yp+40);
        #pragma unroll
        for(int k=0;k<6;++k){ float4 tt=p[k]; yA[4*k]=tt.x; yA[4*k+1]=tt.y; yA[4*k+2]=tt.z; yA[4*k+3]=tt.w; } }
      float du[12];
      #pragma unroll
      for(int u=0;u<12;++u) du[u]=y0[u]*s4.x*c000;
      float shv[3]={s4.y,s4.z,s4.w};
      float tA[8];
      #pragma unroll
      for(int u=0;u<8;++u){
        float sa=0.f;
        #pragma unroll
        for(int a=0;a<3;++a)
          #pragma unroll
          for(int b=0;b<3;++b) sa+=yA[3*u+a]*shv[b]*cgt.v[CG110+3*a+b];
        tA[u]=sa;
      }
      #pragma unroll
      for(int k=0;k<20;++k){
        float4 w4=lerp4(A[k],B[k],fr);
        float wa[4]={w4.x,w4.y,w4.z,w4.w};
        #pragma unroll
        for(int t4=0;t4<4;++t4){
          int c=4*k+t4;
          if (c<8) ef[0]+=wa[t4]*tA[c];
          else { int loc=c-8; ef[1+loc%6]+=wa[t4]*du[loc/6]; }
        }
      }
    } else {
      float y1[4];
      { float4 tt=*(const float4*)(yp+12); y1[0]=tt.x;y1[1]=tt.y;y1[2]=tt.z;y1[3]=tt.w; }
      float yC[24];
      { const float4* p=(const float4*)(yp+16);
        #pragma unroll
        for(int k=0;k<6;++k){ float4 tt=p[k]; yC[4*k]=tt.x; yC[4*k+1]=tt.y; yC[4*k+2]=tt.z; yC[4*k+3]=tt.w; } }
      float du2[4];
      #pragma unroll
      for(int u=0;u<4;++u) du2[u]=y1[u]*s4.x*c000;
      float shv[3]={s4.y,s4.z,s4.w};
      float tC[8];
      #pragma unroll
      for(int u=0;u<8;++u){
        float sc=0.f;
        #pragma unroll
        for(int a=0;a<3;++a)
          #pragma unroll
          for(int b=0;b<3;++b) sc+=yC[3*u+a]*shv[b]*cgt.v[CG110+3*a+b];
        tC[u]=sc;
      }
      const float4* A1=A+20; const float4* B1=B+20;
      #pragma unroll
      for(int k=0;k<18;++k){
        float4 w4=lerp4(A1[k],B1[k],fr);
        float wa[4]={w4.x,w4.y,w4.z,w4.w};
        #pragma unroll
        for(int t4=0;t4<4;++t4){
          int c=80+4*k+t4;
          if (c<104){ int loc=c-8; ef[1+loc%6]+=wa[t4]*du2[loc/6-12]; }
          else { int loc2=c-104; ef[1+loc2%6]+=wa[t4]*tC[loc2/6]; }
        }
      }
    }
    // wave-level reduction (batches sorted -> gidx usually wave-uniform)
    int g0 = __shfl(gidx, 0);
    bool uni = __all(gidx == g0);
    if (uni){
      #pragma unroll
      for(int oc=0;oc<7;++oc){
        float v=ef[oc];
        v += __shfl_down(v,32); v += __shfl_down(v,16); v += __shfl_down(v,8);
        v += __shfl_down(v,4);  v += __shfl_down(v,2);  v += __shfl_down(v,1);
        if (lane==0) atomicAdd(&gacc[g0][oc], v);
      }
    } else {
      #pragma unroll
      for(int oc=0;oc<7;++oc) atomicAdd(&gacc[gidx][oc], ef[oc]);
    }
  }
  __syncthreads();
  if (tid<112){
    float v = gacc[tid/7][tid%7];
    if (v != 0.f) atomicAddF(out+tid, v);
  }
}

// ===================== launch =====================
extern "C" void kernel_launch(void* const* d_in, const int* in_sizes, int n_in,
                              void* d_out, int out_size, void* d_ws, size_t ws_size,
                              hipStream_t stream) {
  (void)in_sizes; (void)n_in; (void)out_size;
  const float* pos  = (const float*)d_in[0];
  const int*   batch= (const int*)d_in[1];
  const int*   esrc = (const int*)d_in[2];
  const int*   edst = (const int*)d_in[3];
  const float* w1c  = (const float*)d_in[4];
  const float* w2c  = (const float*)d_in[5];
  const float* w1f  = (const float*)d_in[6];
  const float* w2f  = (const float*)d_in[7];
  float* out = (float*)d_out;
  char* ws = (char*)d_ws;

  const size_t OFF_W2CP = 0;          // 229376
  const size_t OFF_W2FP = 229376;     // 163840 -> 393216
  const size_t OFF_DEG  = 393216;     // 200000 -> 593216
  const size_t OFF_OFF  = 593216;     // 200064 -> 793280
  const size_t OFF_CUR  = 793280;     // 200000 -> 993280
  const size_t OFF_LENS = 993280;     // 2400000 -> 3393280
  const size_t OFF_SRCS = 3393280;    // 2400000 -> 5793280
  const size_t OFF_BATS = 5793280;    // 2400000 -> 8193280
  const size_t OFF_SHS  = 8193280;    // 38400000 -> 46593280
  const size_t OFF_X0   = 46593280;   // 3200000 -> 49793280
  const size_t OFF_X1   = 49793280;   // 16000000 -> 65793280
  const size_t OFF_XG   = 65793280;   // 12800000 -> 78593280
  const size_t OFF_TABC = 78593280;   // 4096*224*4 = 3670016 -> 82263296
  const size_t OFF_TABF = 82263296;   // 4096*160*4 = 2621440 -> 84884736
  const size_t OFF_EF   = 84884736;   // ef1 stripe buffer (capr*320)

  float* w2cp=(float*)(ws+OFF_W2CP);
  float* w2fp=(float*)(ws+OFF_W2FP);
  int*   deg =(int*)(ws+OFF_DEG);
  int*   offp=(int*)(ws+OFF_OFF);
  int*   cur =(int*)(ws+OFF_CUR);
  float* lens=(float*)(ws+OFF_LENS);
  int*   srcs=(int*)(ws+OFF_SRCS);
  int*   bats=(int*)(ws+OFF_BATS);
  float* shs =(float*)(ws+OFF_SHS);
  float* x0  =(float*)(ws+OFF_X0);
  float* x1  =(float*)(ws+OFF_X1);
  float* xg  =(float*)(ws+OFF_XG);
  float* tabC=(float*)(ws+OFF_TABC);
  float* tabF=(float*)(ws+OFF_TABF);

  long long capr = 0;
  if (ws_size > OFF_EF) capr = (long long)((ws_size - OFF_EF) / 320);
  capr = (capr/128)*128;
  if (capr < 128) capr = 128;
  float* ef1 = (float*)(ws + OFF_EF);

  int nstr = 2;
  while (nstr < 200){
    long long nb = (NN + nstr - 1)/nstr;
    long long expect = nb*12;
    if (expect + expect/4 + 1024 <= capr) break;
    nstr++;
  }
  int NB = (NN + nstr - 1)/nstr;
  int tpcBlks = (int)(capr/64);

  static CGTab hostCG;
  build_cg(hostCG);

  hipMemsetAsync(deg, 0, (size_t)NN*4, stream);
  hipMemsetAsync(out, 0, 112*sizeof(float), stream);

  k_pack <<<384, 256, 0, stream>>>(w2c, w2f, w2cp, w2fp);
  k_table<<<384, 256, 0, stream>>>(w1c, w2cp, w1f, w2fp, tabC, tabF);
  k_deg  <<<(NE+255)/256, 256, 0, stream>>>(edst, deg);
  k_scan <<<1, 1024, 0, stream>>>(deg, offp, cur);
  k_geom <<<(NE+255)/256, 256, 0, stream>>>(pos, esrc, edst, batch, cur, lens, shs, srcs, bats);
  k_gather16<<<(NN*16+255)/256, 256, 0, stream>>>(offp, shs, x0);

  for (int s=0; s<nstr; ++s){
    int n0 = s*NB, n1 = n0+NB; if (n1>NN) n1=NN;
    if (n0>=NN) break;
    int nb = n1-n0;
    k_tp_c  <<<tpcBlks, 256, 0, stream>>>(srcs, shs, lens, x0, tabC, ef1, offp, n0, n1, hostCG);
    k_gather80<<<(nb*80+255)/256, 256, 0, stream>>>(offp, ef1, x1, n0, nb);
  }

  k_gate <<<(NN+255)/256, 256, 0, stream>>>(x1, xg);

  k_tp_f <<<(NE+127)/128, 256, 0, stream>>>(srcs, shs, lens, xg, tabF, bats, hostCG, out);
}